// Round 4
// baseline (565.239 us; speedup 1.0000x reference)
//
#include <hip/hip_runtime.h>
#include <math.h>

#define NF        128
#define H_DIM     256
#define NA        200
#define B_SAMPLES 512
#define ALPHA_LR  0.01f
#define B_MIN_C   1e-4f

#define NTHREADS  64      // ONE wave per sample: zero cross-wave sync.
                          // Lane l owns rows {l, l+64, l+128} (+192+l8 dup'd).

#define N_PH1     10
#define N_REFINE  1
#define CG_MAX    40
#define TOL2_LO   4e-4f             // refinement CG tolerance
#define TOL2_P1   1e-3f             // phase-1 CG tolerance floor
#define TOL2_HI   2.5e-2f

typedef _Float16 h2_t __attribute__((ext_vector_type(2)));
typedef unsigned uv4  __attribute__((ext_vector_type(4)));

__device__ __forceinline__ h2_t as_h2(unsigned u){
  union { unsigned u; h2_t h; } c; c.u = u; return c.h;
}
__device__ __forceinline__ unsigned pk_f16(float a, float b){
#if __has_builtin(__builtin_amdgcn_cvt_pkrtz)
  union { decltype(__builtin_amdgcn_cvt_pkrtz(0.f, 0.f)) h; unsigned u; } c;
  c.h = __builtin_amdgcn_cvt_pkrtz(a, b);
  return c.u;
#else
  union { h2_t h; unsigned u; } c;
  c.h = (h2_t){ (_Float16)a, (_Float16)b };
  return c.u;
#endif
}
__device__ __forceinline__ float fdot2(unsigned m, unsigned v, float acc){
#if __has_builtin(__builtin_amdgcn_fdot2)
  return __builtin_amdgcn_fdot2(as_h2(m), as_h2(v), acc, false);
#else
  h2_t a = as_h2(m), b = as_h2(v);
  return fmaf((float)a.y, (float)b.y, fmaf((float)a.x, (float)b.x, acc));
#endif
}

// ---------------- DPP wave-64 reductions (valid in lane 63) ---------------
__device__ __forceinline__ float dpp_wave_sum(float v){
  v += __int_as_float(__builtin_amdgcn_update_dpp(0, __float_as_int(v), 0x111, 0xf, 0xf, false));
  v += __int_as_float(__builtin_amdgcn_update_dpp(0, __float_as_int(v), 0x112, 0xf, 0xf, false));
  v += __int_as_float(__builtin_amdgcn_update_dpp(0, __float_as_int(v), 0x114, 0xf, 0xf, false));
  v += __int_as_float(__builtin_amdgcn_update_dpp(0, __float_as_int(v), 0x118, 0xf, 0xf, false));
  v += __int_as_float(__builtin_amdgcn_update_dpp(0, __float_as_int(v), 0x142, 0xa, 0xf, false));
  v += __int_as_float(__builtin_amdgcn_update_dpp(0, __float_as_int(v), 0x143, 0xc, 0xf, false));
  return v;
}
__device__ __forceinline__ float dpp_wave_min(float v){
  const int PINF = 0x7f800000;
  v = fminf(v, __int_as_float(__builtin_amdgcn_update_dpp(PINF, __float_as_int(v), 0x111, 0xf, 0xf, false)));
  v = fminf(v, __int_as_float(__builtin_amdgcn_update_dpp(PINF, __float_as_int(v), 0x112, 0xf, 0xf, false)));
  v = fminf(v, __int_as_float(__builtin_amdgcn_update_dpp(PINF, __float_as_int(v), 0x114, 0xf, 0xf, false)));
  v = fminf(v, __int_as_float(__builtin_amdgcn_update_dpp(PINF, __float_as_int(v), 0x118, 0xf, 0xf, false)));
  v = fminf(v, __int_as_float(__builtin_amdgcn_update_dpp(PINF, __float_as_int(v), 0x142, 0xa, 0xf, false)));
  v = fminf(v, __int_as_float(__builtin_amdgcn_update_dpp(PINF, __float_as_int(v), 0x143, 0xc, 0xf, false)));
  return v;
}
__device__ __forceinline__ float dpp_wave_max(float v){
  const int NINF = 0xff800000;
  v = fmaxf(v, __int_as_float(__builtin_amdgcn_update_dpp(NINF, __float_as_int(v), 0x111, 0xf, 0xf, false)));
  v = fmaxf(v, __int_as_float(__builtin_amdgcn_update_dpp(NINF, __float_as_int(v), 0x112, 0xf, 0xf, false)));
  v = fmaxf(v, __int_as_float(__builtin_amdgcn_update_dpp(NINF, __float_as_int(v), 0x114, 0xf, 0xf, false)));
  v = fmaxf(v, __int_as_float(__builtin_amdgcn_update_dpp(NINF, __float_as_int(v), 0x118, 0xf, 0xf, false)));
  v = fmaxf(v, __int_as_float(__builtin_amdgcn_update_dpp(NINF, __float_as_int(v), 0x142, 0xa, 0xf, false)));
  v = fmaxf(v, __int_as_float(__builtin_amdgcn_update_dpp(NINF, __float_as_int(v), 0x143, 0xc, 0xf, false)));
  return v;
}
__device__ __forceinline__ float wave_allsum(float v){
  v = dpp_wave_sum(v);
  return __int_as_float(__builtin_amdgcn_readlane(__float_as_int(v), 63));
}
__device__ __forceinline__ float wave_allmin(float v){
  v = dpp_wave_min(v);
  return __int_as_float(__builtin_amdgcn_readlane(__float_as_int(v), 63));
}
__device__ __forceinline__ float wave_allmax(float v){
  v = dpp_wave_max(v);
  return __int_as_float(__builtin_amdgcn_readlane(__float_as_int(v), 63));
}

__device__ __forceinline__ void put_ph(unsigned short* phs, int row, float v){
  phs[row] = (unsigned short)(pk_f16(v, 0.f) & 0xffffu);
}

// ---- hybrid f16 matrix storage -------------------------------------------
// Rows lane, 64+lane : packed f16 in VGPRs (mregA/mregB, 100 dwords each).
// Rows 128..199     : LDS, chunk-major, XOR-swizzled. Chunk c (16B = 8 f16
// cols 8c..8c+7) of row 128+rr at dword offset:
//   c*288 + ( rr<64 ? ((4*rr)^sw) : 256 + ((4*(rr-64))^sw) ),  sw=(c&7)<<2
// Reads at fixed c: 64 distinct swizzled slots (rows 128..191) -> minimal
// bank occupancy; rows 192..199 are 8 slots broadcast to 8 lanes each.

__device__ __forceinline__ void mv_f16(const unsigned* A, const unsigned* Bm,
                                       const unsigned* lm,
                                       const unsigned* __restrict__ phb,
                                       int lane, int l8, float qo[4]){
  float a0=0.f, a1=0.f, a2=0.f, a3=0.f;
  const int l4 = lane*4, h4 = l8*4;
  #pragma unroll
  for (int c = 0; c < 25; ++c){
    const int sw = (c & 7) << 2;
    uv4 pv = *(const uv4*)(phb + 4*c);                       // uniform bcast
    uv4 m2 = *(const uv4*)(lm + c*288 + (l4 ^ sw));          // row 128+lane
    uv4 m3 = *(const uv4*)(lm + c*288 + 256 + (h4 ^ sw));    // row 192+l8
    a0 = fdot2(A [4*c+0],pv.x,a0); a0 = fdot2(A [4*c+1],pv.y,a0);
    a0 = fdot2(A [4*c+2],pv.z,a0); a0 = fdot2(A [4*c+3],pv.w,a0);
    a1 = fdot2(Bm[4*c+0],pv.x,a1); a1 = fdot2(Bm[4*c+1],pv.y,a1);
    a1 = fdot2(Bm[4*c+2],pv.z,a1); a1 = fdot2(Bm[4*c+3],pv.w,a1);
    a2 = fdot2(m2.x,pv.x,a2); a2 = fdot2(m2.y,pv.y,a2);
    a2 = fdot2(m2.z,pv.z,a2); a2 = fdot2(m2.w,pv.w,a2);
    a3 = fdot2(m3.x,pv.x,a3); a3 = fdot2(m3.y,pv.y,a3);
    a3 = fdot2(m3.z,pv.z,a3); a3 = fdot2(m3.w,pv.w,a3);
  }
  qo[0]=a0; qo[1]=a1; qo[2]=a2; qo[3]=a3;
}

// f16 matrix x fp32 vector (phase-1 gradient: exact fixed point of f16 system)
__device__ __forceinline__ void mv_f32h(const unsigned* A, const unsigned* Bm,
                                        const unsigned* lm,
                                        const float* __restrict__ yvp,
                                        int lane, int l8, float qo[4]){
  float a0=0.f, a1=0.f, a2=0.f, a3=0.f;
  const int l4 = lane*4, h4 = l8*4;
  #pragma unroll
  for (int c = 0; c < 25; ++c){
    const int sw = (c & 7) << 2;
    float4 va = *(const float4*)(yvp + 8*c);
    float4 vb = *(const float4*)(yvp + 8*c + 4);
    uv4 m2 = *(const uv4*)(lm + c*288 + (l4 ^ sw));
    uv4 m3 = *(const uv4*)(lm + c*288 + 256 + (h4 ^ sw));
    { h2_t p0=as_h2(A[4*c+0]),p1=as_h2(A[4*c+1]),p2=as_h2(A[4*c+2]),p3=as_h2(A[4*c+3]);
      a0=fmaf((float)p0.x,va.x,a0); a0=fmaf((float)p0.y,va.y,a0);
      a0=fmaf((float)p1.x,va.z,a0); a0=fmaf((float)p1.y,va.w,a0);
      a0=fmaf((float)p2.x,vb.x,a0); a0=fmaf((float)p2.y,vb.y,a0);
      a0=fmaf((float)p3.x,vb.z,a0); a0=fmaf((float)p3.y,vb.w,a0); }
    { h2_t p0=as_h2(Bm[4*c+0]),p1=as_h2(Bm[4*c+1]),p2=as_h2(Bm[4*c+2]),p3=as_h2(Bm[4*c+3]);
      a1=fmaf((float)p0.x,va.x,a1); a1=fmaf((float)p0.y,va.y,a1);
      a1=fmaf((float)p1.x,va.z,a1); a1=fmaf((float)p1.y,va.w,a1);
      a1=fmaf((float)p2.x,vb.x,a1); a1=fmaf((float)p2.y,vb.y,a1);
      a1=fmaf((float)p3.x,vb.z,a1); a1=fmaf((float)p3.y,vb.w,a1); }
    { h2_t p0=as_h2(m2.x),p1=as_h2(m2.y),p2=as_h2(m2.z),p3=as_h2(m2.w);
      a2=fmaf((float)p0.x,va.x,a2); a2=fmaf((float)p0.y,va.y,a2);
      a2=fmaf((float)p1.x,va.z,a2); a2=fmaf((float)p1.y,va.w,a2);
      a2=fmaf((float)p2.x,vb.x,a2); a2=fmaf((float)p2.y,vb.y,a2);
      a2=fmaf((float)p3.x,vb.z,a2); a2=fmaf((float)p3.y,vb.w,a2); }
    { h2_t p0=as_h2(m3.x),p1=as_h2(m3.y),p2=as_h2(m3.z),p3=as_h2(m3.w);
      a3=fmaf((float)p0.x,va.x,a3); a3=fmaf((float)p0.y,va.y,a3);
      a3=fmaf((float)p1.x,va.z,a3); a3=fmaf((float)p1.y,va.w,a3);
      a3=fmaf((float)p2.x,vb.x,a3); a3=fmaf((float)p2.y,vb.y,a3);
      a3=fmaf((float)p3.x,vb.z,a3); a3=fmaf((float)p3.y,vb.w,a3); }
  }
  qo[0]=a0; qo[1]=a1; qo[2]=a2; qo[3]=a3;
}

// exact f32 gradient matvec: per-lane strided row dots from global (L2/L3-hot)
__device__ __forceinline__ void mv_exact(const float* __restrict__ S,
                                         const float* __restrict__ yvp,
                                         int lane, int l8, float qo[4]){
  const float* r0 = S + (size_t)lane*NA;
  const float* r1 = S + (size_t)(64+lane)*NA;
  const float* r2 = S + (size_t)(128+lane)*NA;
  const float* r3 = S + (size_t)(192+l8)*NA;
  float a0=0.f, a1=0.f, a2=0.f, a3=0.f;
  #pragma unroll
  for (int c = 0; c < 25; ++c){
    float4 va = *(const float4*)(yvp + 8*c);
    float4 vb = *(const float4*)(yvp + 8*c + 4);
    float4 g0a = *(const float4*)(r0 + 8*c), g0b = *(const float4*)(r0 + 8*c + 4);
    float4 g1a = *(const float4*)(r1 + 8*c), g1b = *(const float4*)(r1 + 8*c + 4);
    float4 g2a = *(const float4*)(r2 + 8*c), g2b = *(const float4*)(r2 + 8*c + 4);
    float4 g3a = *(const float4*)(r3 + 8*c), g3b = *(const float4*)(r3 + 8*c + 4);
    a0=fmaf(g0a.x,va.x,a0); a0=fmaf(g0a.y,va.y,a0); a0=fmaf(g0a.z,va.z,a0); a0=fmaf(g0a.w,va.w,a0);
    a0=fmaf(g0b.x,vb.x,a0); a0=fmaf(g0b.y,vb.y,a0); a0=fmaf(g0b.z,vb.z,a0); a0=fmaf(g0b.w,vb.w,a0);
    a1=fmaf(g1a.x,va.x,a1); a1=fmaf(g1a.y,va.y,a1); a1=fmaf(g1a.z,va.z,a1); a1=fmaf(g1a.w,va.w,a1);
    a1=fmaf(g1b.x,vb.x,a1); a1=fmaf(g1b.y,vb.y,a1); a1=fmaf(g1b.z,vb.z,a1); a1=fmaf(g1b.w,vb.w,a1);
    a2=fmaf(g2a.x,va.x,a2); a2=fmaf(g2a.y,va.y,a2); a2=fmaf(g2a.z,va.z,a2); a2=fmaf(g2a.w,va.w,a2);
    a2=fmaf(g2b.x,vb.x,a2); a2=fmaf(g2b.y,vb.y,a2); a2=fmaf(g2b.z,vb.z,a2); a2=fmaf(g2b.w,vb.w,a2);
    a3=fmaf(g3a.x,va.x,a3); a3=fmaf(g3a.y,va.y,a3); a3=fmaf(g3a.z,va.z,a3); a3=fmaf(g3a.w,va.w,a3);
    a3=fmaf(g3b.x,vb.x,a3); a3=fmaf(g3b.y,vb.y,a3); a3=fmaf(g3b.z,vb.z,a3); a3=fmaf(g3b.w,vb.w,a3);
  }
  qo[0]=a0; qo[1]=a1; qo[2]=a2; qo[3]=a3;
}

extern "C" __global__ __launch_bounds__(NTHREADS)
void rb_kernel(const float* __restrict__ x,  const float* __restrict__ Sigma,
               const float* __restrict__ W1, const float* __restrict__ b1,
               const float* __restrict__ W2, const float* __restrict__ b2,
               float* __restrict__ out) {
  // 28800 + 400 + 800 = 30000 B static LDS (well under the 64 KiB limit);
  // 2 blocks/CU -> 60 KB of 160 KB.
  __shared__ __align__(16) unsigned lds_mat[7200];    // f16 rows 128..199
  __shared__ __align__(16) unsigned ph[100];          // packed f16 vec (200 h)
  __shared__ __align__(16) float    yv[NA];

  const int  lane = threadIdx.x;
  const int  s    = blockIdx.x;
  const bool has3 = lane < 8;
  const int  l8   = lane & 7;
  const float* S  = Sigma + (size_t)s * NA * NA;
  unsigned short* phs = (unsigned short*)ph;

  // ---- MLP in lds_mat-aliased scratch (staged over later) ----
  float* xs = (float*)lds_mat;            // 128 f
  float* hs = ((float*)lds_mat) + NF;     // 256 f
  xs[lane]      = x[s*NF + lane];
  xs[lane + 64] = x[s*NF + 64 + lane];
  __syncthreads();
  #pragma unroll
  for (int i = 0; i < 4; ++i){
    const int t = lane + 64*i;
    const float4* w = (const float4*)(W1 + (size_t)t*NF);
    float acc = b1[t];
    #pragma unroll 8
    for (int j = 0; j < NF/4; ++j){
      float4 ww = w[j]; float4 xx = ((const float4*)xs)[j];
      acc = fmaf(ww.x,xx.x,acc); acc = fmaf(ww.y,xx.y,acc);
      acc = fmaf(ww.z,xx.z,acc); acc = fmaf(ww.w,xx.w,acc);
    }
    hs[t] = (acc >= 0.f) ? acc : ALPHA_LR * acc;
  }
  __syncthreads();
  float lg[4];
  #pragma unroll
  for (int i = 0; i < 4; ++i){
    const int r = (i < 3) ? (lane + 64*i) : (192 + l8);
    const float4* w = (const float4*)(W2 + (size_t)r*H_DIM);
    float acc = b2[r];
    #pragma unroll 8
    for (int j = 0; j < H_DIM/4; ++j){
      float4 ww = w[j]; float4 hh = ((const float4*)hs)[j];
      acc = fmaf(ww.x,hh.x,acc); acc = fmaf(ww.y,hh.y,acc);
      acc = fmaf(ww.z,hh.z,acc); acc = fmaf(ww.w,hh.w,acc);
    }
    lg[i] = acc;
  }
  if (!has3) lg[3] = -INFINITY;
  __syncthreads();                        // hs reads done; lds_mat free

  // ---- stage VGPR rows (lane, 64+lane) as packed f16 ----
  unsigned mregA[100], mregB[100];
  {
    const float4* ra = (const float4*)(S + (size_t)lane*NA);
    const float4* rb = (const float4*)(S + (size_t)(64+lane)*NA);
    #pragma unroll
    for (int k = 0; k < 50; ++k){
      float4 wa = ra[k];
      mregA[2*k]   = pk_f16(wa.x, wa.y);
      mregA[2*k+1] = pk_f16(wa.z, wa.w);
      float4 wb = rb[k];
      mregB[2*k]   = pk_f16(wb.x, wb.y);
      mregB[2*k+1] = pk_f16(wb.z, wb.w);
    }
  }

  // ---- stage rows 128..199 -> f16 LDS (coalesced 32B/lane global reads) ----
  for (int i = 0; i < 28; ++i){
    const int e = i*64 + lane;            // entry = rr*25 + c, rr in [0,72)
    const int rr = e/25, c = e - rr*25;
    const float4* gp = (const float4*)(S + (size_t)(128+rr)*NA + 8*c);
    float4 f0 = gp[0], f1 = gp[1];
    uv4 w;
    w.x = pk_f16(f0.x,f0.y); w.y = pk_f16(f0.z,f0.w);
    w.z = pk_f16(f1.x,f1.y); w.w = pk_f16(f1.z,f1.w);
    const int sw = (c & 7) << 2;
    const int off = (rr < 64) ? ((4*rr) ^ sw) : (256 + ((4*(rr-64)) ^ sw));
    *(uv4*)(lds_mat + c*288 + off) = w;
  }
  if (has3){                              // tail entries 1792..1799
    const int e = 1792 + lane;
    const int rr = e/25, c = e - rr*25;
    const float4* gp = (const float4*)(S + (size_t)(128+rr)*NA + 8*c);
    float4 f0 = gp[0], f1 = gp[1];
    uv4 w;
    w.x = pk_f16(f0.x,f0.y); w.y = pk_f16(f0.z,f0.w);
    w.z = pk_f16(f1.x,f1.y); w.w = pk_f16(f1.z,f1.w);
    const int sw = (c & 7) << 2;
    const int off = (rr < 64) ? ((4*rr) ^ sw) : (256 + ((4*(rr-64)) ^ sw));
    *(uv4*)(lds_mat + c*288 + off) = w;
  }

  float sd[4];
  sd[0] = S[(size_t)lane*201];
  sd[1] = S[(size_t)(64+lane)*201];
  sd[2] = S[(size_t)(128+lane)*201];
  sd[3] = has3 ? S[(size_t)(192+lane)*201] : 1.f;

  // ---- softmax -> b (output 2); clamp+renorm -> b_ (register-only) ----
  float mx = wave_allmax(fmaxf(fmaxf(lg[0],lg[1]), fmaxf(lg[2],lg[3])));
  float ex[4];
  #pragma unroll
  for (int i = 0; i < 4; ++i) ex[i] = expf(lg[i] - mx);   // ex[3]=0 if !has3
  float es = wave_allsum(((ex[0]+ex[1]) + (ex[2]+ex[3])));
  float bsoft[4], bcl[4];
  #pragma unroll
  for (int i = 0; i < 4; ++i) bsoft[i] = ex[i]/es;
  float* outb = out + (size_t)B_SAMPLES*NA + (size_t)s*NA;
  outb[lane] = bsoft[0]; outb[lane+64] = bsoft[1]; outb[lane+128] = bsoft[2];
  if (has3) outb[192+lane] = bsoft[3];
  bcl[0] = fmaxf(bsoft[0], B_MIN_C); bcl[1] = fmaxf(bsoft[1], B_MIN_C);
  bcl[2] = fmaxf(bsoft[2], B_MIN_C);
  bcl[3] = has3 ? fmaxf(bsoft[3], B_MIN_C) : 0.f;
  float bs = wave_allsum((bcl[0]+bcl[1]) + (bcl[2]+bcl[3]));
  float b_[4];
  #pragma unroll
  for (int i = 0; i < 4; ++i) b_[i] = bcl[i]/bs;          // b_[3]=0 if !has3

  put_ph(phs, lane,      b_[0]);
  put_ph(phs, lane+64,   b_[1]);
  put_ph(phs, lane+128,  b_[2]);
  if (has3) put_ph(phs, 192+lane, b_[3]);

  // ---- y0 = bc / sqrt(bc^T S bc) ----
  float y[4], q[4];
  __syncthreads();                        // mat + ph visible
  mv_f16(mregA, mregB, lds_mat, ph, lane, l8, q);
  float quad = wave_allsum(fmaf(b_[0],q[0], fmaf(b_[1],q[1],
                           fmaf(b_[2],q[2], b_[3]*q[3]))));
  float rq0 = 1.f/sqrtf(quad);
  y[0] = b_[0]*rq0; y[1] = b_[1]*rq0; y[2] = b_[2]*rq0;
  y[3] = has3 ? b_[3]*rq0 : 1.f;          // masked lanes keep benign y=1
  yv[lane] = y[0]; yv[lane+64] = y[1]; yv[lane+128] = y[2];
  if (has3) yv[192+lane] = y[3];

  // ---- damped inexact Newton (classic PCG inner solver, wave-local) ----
  float gg0 = 1.f;
  bool  ph1done = false;
  int   nexact  = 0;
  for (int it = 0; it < N_PH1 + N_REFINE; ++it){
    if (nexact >= N_REFINE) break;
    const bool exact = ph1done;
    if (exact) ++nexact;

    __syncthreads();                      // yv current
    if (exact){
      mv_exact(S, yv, lane, l8, q);       // exact f32 gradient (once/sample)
    } else {
      mv_f32h(mregA, mregB, lds_mat, yv, lane, l8, q);
    }

    // --- Newton init ---
    float g[4], d[4], mi[4];
    #pragma unroll
    for (int i = 0; i < 4; ++i){
      g[i]  = q[i] - b_[i]/y[i];          // masked i=3: b=0,y=1 -> finite
      d[i]  = b_[i]/(y[i]*y[i]);
      mi[i] = 1.f/(sd[i] + d[i]);
    }
    float gg = wave_allsum((g[0]*g[0] + g[1]*g[1]) + (g[2]*g[2]
                           + (has3 ? g[3]*g[3] : 0.f)));
    float rz = wave_allsum((g[0]*g[0]*mi[0] + g[1]*g[1]*mi[1])
                           + (g[2]*g[2]*mi[2] + (has3 ? g[3]*g[3]*mi[3] : 0.f)));
    if (it == 0) gg0 = fmaxf(gg, 1e-30f);
    float tol2 = exact ? TOL2_LO
                       : fminf(TOL2_HI, fmaxf(TOL2_P1, 4.f * (gg / gg0)));

    if (gg > 1e-24f){
      const float cinv = rsqrtf(gg);
      const float csc  = sqrtf(gg);
      float r_[4], z[4], pj[4], dy[4];
      #pragma unroll
      for (int i = 0; i < 4; ++i){
        r_[i] = -g[i]*cinv;
        z[i]  = mi[i]*r_[i];
        if (i == 3) z[3] = has3 ? z[3] : 0.f;   // keep masked pj chain at 0
        pj[i] = z[i];
        dy[i] = 0.f;
      }
      put_ph(phs, lane,     pj[0]);
      put_ph(phs, lane+64,  pj[1]);
      put_ph(phs, lane+128, pj[2]);
      if (has3) put_ph(phs, 192+lane, pj[3]);
      rz = rz * cinv * cinv;
      const float rz0 = rz;

      for (int j = 0; j < CG_MAX; ++j){
        __syncthreads();                  // ph visible (single wave: cheap)
        float qp[4];
        mv_f16(mregA, mregB, lds_mat, ph, lane, l8, qp);
        float qf[4], u[4];
        #pragma unroll
        for (int i = 0; i < 4; ++i){
          qf[i] = fmaf(d[i], pj[i], qp[i]);
          u[i]  = mi[i]*qf[i];
        }
        u[3] = has3 ? u[3] : 0.f;
        float cpq = wave_allsum((pj[0]*qf[0] + pj[1]*qf[1])
                              + (pj[2]*qf[2] + pj[3]*qf[3]));   // pj[3]=0 masked
        float crq = wave_allsum((r_[0]*u[0] + r_[1]*u[1])
                              + (r_[2]*u[2] + r_[3]*u[3]));
        float cqq = wave_allsum((qf[0]*u[0] + qf[1]*u[1])
                              + (qf[2]*u[2] + qf[3]*u[3]));
        float alpha = rz / cpq;
        float rznew = fmaxf(fmaf(alpha*alpha, cqq, fmaf(-2.f*alpha, crq, rz)), 0.f);
        #pragma unroll
        for (int i = 0; i < 4; ++i){
          dy[i] = fmaf( alpha, pj[i], dy[i]);
          r_[i] = fmaf(-alpha, qf[i], r_[i]);
          z[i]  = mi[i]*r_[i];
        }
        z[3] = has3 ? z[3] : 0.f;
        bool brk = (rznew <= tol2 * rz0) || (j == CG_MAX - 1);
        if (!brk){
          float beta = rznew / rz;
          #pragma unroll
          for (int i = 0; i < 4; ++i) pj[i] = fmaf(beta, pj[i], z[i]);
          put_ph(phs, lane,     pj[0]);
          put_ph(phs, lane+64,  pj[1]);
          put_ph(phs, lane+128, pj[2]);
          if (has3) put_ph(phs, 192+lane, pj[3]);
        }
        rz = rznew;
        if (brk) break;
      }

      // --- unscale dy; damped step keeping y > 0 (reference semantics) ---
      float ratio = 1e30f;
      #pragma unroll
      for (int i = 0; i < 4; ++i){
        dy[i] *= csc;                     // dy[3]=0 for masked lanes
        ratio = fminf(ratio, (dy[i] < 0.f) ? (-y[i]/dy[i]) : 1e30f);
      }
      float mr = wave_allmin(ratio);
      float t = fminf(1.f, 0.9f * mr);
      #pragma unroll
      for (int i = 0; i < 4; ++i) y[i] = fmaxf(fmaf(t, dy[i], y[i]), 1e-12f);
      yv[lane] = y[0]; yv[lane+64] = y[1]; yv[lane+128] = y[2];
      if (has3) yv[192+lane] = y[3];
    }

    if (!exact && (gg <= 1e-8f * gg0 || it + 1 >= N_PH1)) ph1done = true;
  }

  // ---- z = y / sum(y) (output 1) ----
  float ys = wave_allsum((y[0] + y[1]) + (y[2] + (has3 ? y[3] : 0.f)));
  float* outz = out + (size_t)s*NA;
  outz[lane] = y[0]/ys; outz[lane+64] = y[1]/ys; outz[lane+128] = y[2]/ys;
  if (has3) outz[192+lane] = y[3]/ys;
}

extern "C" void kernel_launch(void* const* d_in, const int* in_sizes, int n_in,
                              void* d_out, int out_size, void* d_ws, size_t ws_size,
                              hipStream_t stream) {
  const float* x     = (const float*)d_in[0];
  const float* Sigma = (const float*)d_in[1];
  const float* W1    = (const float*)d_in[2];
  const float* b1    = (const float*)d_in[3];
  const float* W2    = (const float*)d_in[4];
  const float* b2    = (const float*)d_in[5];
  float* out = (float*)d_out;
  hipLaunchKernelGGL(rb_kernel, dim3(B_SAMPLES), dim3(NTHREADS), 0, stream,
                     x, Sigma, W1, b1, W2, b2, out);
}

// Round 6
// 406.108 us; speedup vs baseline: 1.3918x; 1.3918x over previous
//
#include <hip/hip_runtime.h>
#include <math.h>

#define NF        128
#define H_DIM     256
#define NA        200
#define B_SAMPLES 512
#define ALPHA_LR  0.01f
#define B_MIN_C   1e-4f

#define NTHREADS  64      // ONE wave per sample: zero cross-wave sync.
                          // Lane l owns rows {l (VGPR), 64+l, 128+l} (+192+l8).

#define N_PH1     10
#define N_REFINE  1
#define CG_MAX    40
#define TOL2_LO   4e-4f             // refinement CG tolerance
#define TOL2_P1   1e-3f             // phase-1 CG tolerance floor
#define TOL2_HI   2.5e-2f

typedef _Float16 h2_t __attribute__((ext_vector_type(2)));
typedef unsigned uv4  __attribute__((ext_vector_type(4)));

__device__ __forceinline__ h2_t as_h2(unsigned u){
  union { unsigned u; h2_t h; } c; c.u = u; return c.h;
}
__device__ __forceinline__ unsigned pk_f16(float a, float b){
#if __has_builtin(__builtin_amdgcn_cvt_pkrtz)
  union { decltype(__builtin_amdgcn_cvt_pkrtz(0.f, 0.f)) h; unsigned u; } c;
  c.h = __builtin_amdgcn_cvt_pkrtz(a, b);
  return c.u;
#else
  union { h2_t h; unsigned u; } c;
  c.h = (h2_t){ (_Float16)a, (_Float16)b };
  return c.u;
#endif
}
__device__ __forceinline__ float fdot2(unsigned m, unsigned v, float acc){
#if __has_builtin(__builtin_amdgcn_fdot2)
  return __builtin_amdgcn_fdot2(as_h2(m), as_h2(v), acc, false);
#else
  h2_t a = as_h2(m), b = as_h2(v);
  return fmaf((float)a.y, (float)b.y, fmaf((float)a.x, (float)b.x, acc));
#endif
}

// ---------------- DPP wave-64 reductions (valid in lane 63) ---------------
__device__ __forceinline__ float dpp_wave_sum(float v){
  v += __int_as_float(__builtin_amdgcn_update_dpp(0, __float_as_int(v), 0x111, 0xf, 0xf, false));
  v += __int_as_float(__builtin_amdgcn_update_dpp(0, __float_as_int(v), 0x112, 0xf, 0xf, false));
  v += __int_as_float(__builtin_amdgcn_update_dpp(0, __float_as_int(v), 0x114, 0xf, 0xf, false));
  v += __int_as_float(__builtin_amdgcn_update_dpp(0, __float_as_int(v), 0x118, 0xf, 0xf, false));
  v += __int_as_float(__builtin_amdgcn_update_dpp(0, __float_as_int(v), 0x142, 0xa, 0xf, false));
  v += __int_as_float(__builtin_amdgcn_update_dpp(0, __float_as_int(v), 0x143, 0xc, 0xf, false));
  return v;
}
__device__ __forceinline__ float dpp_wave_min(float v){
  const int PINF = 0x7f800000;
  v = fminf(v, __int_as_float(__builtin_amdgcn_update_dpp(PINF, __float_as_int(v), 0x111, 0xf, 0xf, false)));
  v = fminf(v, __int_as_float(__builtin_amdgcn_update_dpp(PINF, __float_as_int(v), 0x112, 0xf, 0xf, false)));
  v = fminf(v, __int_as_float(__builtin_amdgcn_update_dpp(PINF, __float_as_int(v), 0x114, 0xf, 0xf, false)));
  v = fminf(v, __int_as_float(__builtin_amdgcn_update_dpp(PINF, __float_as_int(v), 0x118, 0xf, 0xf, false)));
  v = fminf(v, __int_as_float(__builtin_amdgcn_update_dpp(PINF, __float_as_int(v), 0x142, 0xa, 0xf, false)));
  v = fminf(v, __int_as_float(__builtin_amdgcn_update_dpp(PINF, __float_as_int(v), 0x143, 0xc, 0xf, false)));
  return v;
}
__device__ __forceinline__ float dpp_wave_max(float v){
  const int NINF = 0xff800000;
  v = fmaxf(v, __int_as_float(__builtin_amdgcn_update_dpp(NINF, __float_as_int(v), 0x111, 0xf, 0xf, false)));
  v = fmaxf(v, __int_as_float(__builtin_amdgcn_update_dpp(NINF, __float_as_int(v), 0x112, 0xf, 0xf, false)));
  v = fmaxf(v, __int_as_float(__builtin_amdgcn_update_dpp(NINF, __float_as_int(v), 0x114, 0xf, 0xf, false)));
  v = fmaxf(v, __int_as_float(__builtin_amdgcn_update_dpp(NINF, __float_as_int(v), 0x118, 0xf, 0xf, false)));
  v = fmaxf(v, __int_as_float(__builtin_amdgcn_update_dpp(NINF, __float_as_int(v), 0x142, 0xa, 0xf, false)));
  v = fmaxf(v, __int_as_float(__builtin_amdgcn_update_dpp(NINF, __float_as_int(v), 0x143, 0xc, 0xf, false)));
  return v;
}
__device__ __forceinline__ float wave_allsum(float v){
  v = dpp_wave_sum(v);
  return __int_as_float(__builtin_amdgcn_readlane(__float_as_int(v), 63));
}
__device__ __forceinline__ float wave_allmin(float v){
  v = dpp_wave_min(v);
  return __int_as_float(__builtin_amdgcn_readlane(__float_as_int(v), 63));
}
__device__ __forceinline__ float wave_allmax(float v){
  v = dpp_wave_max(v);
  return __int_as_float(__builtin_amdgcn_readlane(__float_as_int(v), 63));
}

__device__ __forceinline__ void put_ph(unsigned short* phs, int row, float v){
  phs[row] = (unsigned short)(pk_f16(v, 0.f) & 0xffffu);
}

// ---- hybrid f16 matrix storage -------------------------------------------
// Row lane       : packed f16 in VGPRs (mregA, 100 dwords).
// Rows 64..199   : LDS, chunk-major. Chunk c (16B = 8 f16 cols 8c..8c+7) of
//                  row 64+t at dword offset c*544 + 4*t, t in [0,136).
// Reads at fixed c: lanes hit consecutive 16B slots (t=lane / t=64+lane)
// -> contiguous 1KB wave-op, conflict-free. Rows 192..199 (t=128+l8) are
// 8 slots spanning exactly 128B -> each bank once.

__device__ __forceinline__ void mv_f16(const unsigned* A, const unsigned* lm,
                                       const unsigned* __restrict__ phb,
                                       int lane, int l8, float qo[4]){
  float a0=0.f, a1=0.f, a2=0.f, a3=0.f;
  #pragma unroll
  for (int c = 0; c < 25; ++c){
    const unsigned* base = lm + c*544;
    uv4 pv = *(const uv4*)(phb + 4*c);                   // uniform bcast
    uv4 m1 = *(const uv4*)(base + 4*lane);               // row 64+lane
    uv4 m2 = *(const uv4*)(base + 4*(64+lane));          // row 128+lane
    uv4 m3 = *(const uv4*)(base + 4*(128+l8));           // row 192+l8
    a0 = fdot2(A[4*c+0],pv.x,a0); a0 = fdot2(A[4*c+1],pv.y,a0);
    a0 = fdot2(A[4*c+2],pv.z,a0); a0 = fdot2(A[4*c+3],pv.w,a0);
    a1 = fdot2(m1.x,pv.x,a1); a1 = fdot2(m1.y,pv.y,a1);
    a1 = fdot2(m1.z,pv.z,a1); a1 = fdot2(m1.w,pv.w,a1);
    a2 = fdot2(m2.x,pv.x,a2); a2 = fdot2(m2.y,pv.y,a2);
    a2 = fdot2(m2.z,pv.z,a2); a2 = fdot2(m2.w,pv.w,a2);
    a3 = fdot2(m3.x,pv.x,a3); a3 = fdot2(m3.y,pv.y,a3);
    a3 = fdot2(m3.z,pv.z,a3); a3 = fdot2(m3.w,pv.w,a3);
  }
  qo[0]=a0; qo[1]=a1; qo[2]=a2; qo[3]=a3;
}

// f16 matrix x fp32 vector (phase-1 gradient: exact fixed point of f16 system)
__device__ __forceinline__ void mv_f32h(const unsigned* A, const unsigned* lm,
                                        const float* __restrict__ yvp,
                                        int lane, int l8, float qo[4]){
  float a0=0.f, a1=0.f, a2=0.f, a3=0.f;
  #pragma unroll
  for (int c = 0; c < 25; ++c){
    const unsigned* base = lm + c*544;
    float4 va = *(const float4*)(yvp + 8*c);
    float4 vb = *(const float4*)(yvp + 8*c + 4);
    uv4 m1 = *(const uv4*)(base + 4*lane);
    uv4 m2 = *(const uv4*)(base + 4*(64+lane));
    uv4 m3 = *(const uv4*)(base + 4*(128+l8));
    { h2_t p0=as_h2(A[4*c+0]),p1=as_h2(A[4*c+1]),p2=as_h2(A[4*c+2]),p3=as_h2(A[4*c+3]);
      a0=fmaf((float)p0.x,va.x,a0); a0=fmaf((float)p0.y,va.y,a0);
      a0=fmaf((float)p1.x,va.z,a0); a0=fmaf((float)p1.y,va.w,a0);
      a0=fmaf((float)p2.x,vb.x,a0); a0=fmaf((float)p2.y,vb.y,a0);
      a0=fmaf((float)p3.x,vb.z,a0); a0=fmaf((float)p3.y,vb.w,a0); }
    { h2_t p0=as_h2(m1.x),p1=as_h2(m1.y),p2=as_h2(m1.z),p3=as_h2(m1.w);
      a1=fmaf((float)p0.x,va.x,a1); a1=fmaf((float)p0.y,va.y,a1);
      a1=fmaf((float)p1.x,va.z,a1); a1=fmaf((float)p1.y,va.w,a1);
      a1=fmaf((float)p2.x,vb.x,a1); a1=fmaf((float)p2.y,vb.y,a1);
      a1=fmaf((float)p3.x,vb.z,a1); a1=fmaf((float)p3.y,vb.w,a1); }
    { h2_t p0=as_h2(m2.x),p1=as_h2(m2.y),p2=as_h2(m2.z),p3=as_h2(m2.w);
      a2=fmaf((float)p0.x,va.x,a2); a2=fmaf((float)p0.y,va.y,a2);
      a2=fmaf((float)p1.x,va.z,a2); a2=fmaf((float)p1.y,va.w,a2);
      a2=fmaf((float)p2.x,vb.x,a2); a2=fmaf((float)p2.y,vb.y,a2);
      a2=fmaf((float)p3.x,vb.z,a2); a2=fmaf((float)p3.y,vb.w,a2); }
    { h2_t p0=as_h2(m3.x),p1=as_h2(m3.y),p2=as_h2(m3.z),p3=as_h2(m3.w);
      a3=fmaf((float)p0.x,va.x,a3); a3=fmaf((float)p0.y,va.y,a3);
      a3=fmaf((float)p1.x,va.z,a3); a3=fmaf((float)p1.y,va.w,a3);
      a3=fmaf((float)p2.x,vb.x,a3); a3=fmaf((float)p2.y,vb.y,a3);
      a3=fmaf((float)p3.x,vb.z,a3); a3=fmaf((float)p3.y,vb.w,a3); }
  }
  qo[0]=a0; qo[1]=a1; qo[2]=a2; qo[3]=a3;
}

// exact f32 gradient matvec: per-lane strided row dots from global (L2/L3-hot)
__device__ __forceinline__ void mv_exact(const float* __restrict__ S,
                                         const float* __restrict__ yvp,
                                         int lane, int l8, float qo[4]){
  const float* r0 = S + (size_t)lane*NA;
  const float* r1 = S + (size_t)(64+lane)*NA;
  const float* r2 = S + (size_t)(128+lane)*NA;
  const float* r3 = S + (size_t)(192+l8)*NA;
  float a0=0.f, a1=0.f, a2=0.f, a3=0.f;
  #pragma unroll
  for (int c = 0; c < 25; ++c){
    float4 va = *(const float4*)(yvp + 8*c);
    float4 vb = *(const float4*)(yvp + 8*c + 4);
    float4 g0a = *(const float4*)(r0 + 8*c), g0b = *(const float4*)(r0 + 8*c + 4);
    float4 g1a = *(const float4*)(r1 + 8*c), g1b = *(const float4*)(r1 + 8*c + 4);
    float4 g2a = *(const float4*)(r2 + 8*c), g2b = *(const float4*)(r2 + 8*c + 4);
    float4 g3a = *(const float4*)(r3 + 8*c), g3b = *(const float4*)(r3 + 8*c + 4);
    a0=fmaf(g0a.x,va.x,a0); a0=fmaf(g0a.y,va.y,a0); a0=fmaf(g0a.z,va.z,a0); a0=fmaf(g0a.w,va.w,a0);
    a0=fmaf(g0b.x,vb.x,a0); a0=fmaf(g0b.y,vb.y,a0); a0=fmaf(g0b.z,vb.z,a0); a0=fmaf(g0b.w,vb.w,a0);
    a1=fmaf(g1a.x,va.x,a1); a1=fmaf(g1a.y,va.y,a1); a1=fmaf(g1a.z,va.z,a1); a1=fmaf(g1a.w,va.w,a1);
    a1=fmaf(g1b.x,vb.x,a1); a1=fmaf(g1b.y,vb.y,a1); a1=fmaf(g1b.z,vb.z,a1); a1=fmaf(g1b.w,vb.w,a1);
    a2=fmaf(g2a.x,va.x,a2); a2=fmaf(g2a.y,va.y,a2); a2=fmaf(g2a.z,va.z,a2); a2=fmaf(g2a.w,va.w,a2);
    a2=fmaf(g2b.x,vb.x,a2); a2=fmaf(g2b.y,vb.y,a2); a2=fmaf(g2b.z,vb.z,a2); a2=fmaf(g2b.w,vb.w,a2);
    a3=fmaf(g3a.x,va.x,a3); a3=fmaf(g3a.y,va.y,a3); a3=fmaf(g3a.z,va.z,a3); a3=fmaf(g3a.w,va.w,a3);
    a3=fmaf(g3b.x,vb.x,a3); a3=fmaf(g3b.y,vb.y,a3); a3=fmaf(g3b.z,vb.z,a3); a3=fmaf(g3b.w,vb.w,a3);
  }
  qo[0]=a0; qo[1]=a1; qo[2]=a2; qo[3]=a3;
}

extern "C" __global__ __launch_bounds__(NTHREADS)
void rb_kernel(const float* __restrict__ x,  const float* __restrict__ Sigma,
               const float* __restrict__ W1, const float* __restrict__ b1,
               const float* __restrict__ W2, const float* __restrict__ b2,
               float* __restrict__ out) {
  // 54400 + 400 + 800 = 55600 B static LDS (< 64 KiB); 2 blocks/CU fits 160 KiB.
  __shared__ __align__(16) unsigned lds_mat[13600];   // f16 rows 64..199
  __shared__ __align__(16) unsigned ph[100];          // packed f16 vec (200 h)
  __shared__ __align__(16) float    yv[NA];

  const int  lane = threadIdx.x;
  const int  s    = blockIdx.x;
  const bool has3 = lane < 8;
  const int  l8   = lane & 7;
  const float* S  = Sigma + (size_t)s * NA * NA;
  unsigned short* phs = (unsigned short*)ph;

  // ---- MLP in lds_mat-aliased scratch (staged over later) ----
  float* xs = (float*)lds_mat;            // 128 f
  float* hs = ((float*)lds_mat) + NF;     // 256 f
  xs[lane]      = x[s*NF + lane];
  xs[lane + 64] = x[s*NF + 64 + lane];
  __syncthreads();
  #pragma unroll
  for (int i = 0; i < 4; ++i){
    const int t = lane + 64*i;
    const float4* w = (const float4*)(W1 + (size_t)t*NF);
    float acc = b1[t];
    #pragma unroll 8
    for (int j = 0; j < NF/4; ++j){
      float4 ww = w[j]; float4 xx = ((const float4*)xs)[j];
      acc = fmaf(ww.x,xx.x,acc); acc = fmaf(ww.y,xx.y,acc);
      acc = fmaf(ww.z,xx.z,acc); acc = fmaf(ww.w,xx.w,acc);
    }
    hs[t] = (acc >= 0.f) ? acc : ALPHA_LR * acc;
  }
  __syncthreads();
  float lg[4];
  #pragma unroll
  for (int i = 0; i < 4; ++i){
    const int r = (i < 3) ? (lane + 64*i) : (192 + l8);
    const float4* w = (const float4*)(W2 + (size_t)r*H_DIM);
    float acc = b2[r];
    #pragma unroll 8
    for (int j = 0; j < H_DIM/4; ++j){
      float4 ww = w[j]; float4 hh = ((const float4*)hs)[j];
      acc = fmaf(ww.x,hh.x,acc); acc = fmaf(ww.y,hh.y,acc);
      acc = fmaf(ww.z,hh.z,acc); acc = fmaf(ww.w,hh.w,acc);
    }
    lg[i] = acc;
  }
  if (!has3) lg[3] = -INFINITY;
  __syncthreads();                        // hs reads done; lds_mat free

  // ---- stage VGPR row (lane) as packed f16 ----
  unsigned mregA[100];
  {
    const float4* ra = (const float4*)(S + (size_t)lane*NA);
    #pragma unroll
    for (int k = 0; k < 50; ++k){
      float4 wa = ra[k];
      mregA[2*k]   = pk_f16(wa.x, wa.y);
      mregA[2*k+1] = pk_f16(wa.z, wa.w);
    }
  }

  // ---- stage rows 64..199 -> f16 LDS (conflict-free chunk-major writes) ----
  // entry e = c*136 + t: consecutive lanes -> consecutive 16B slots.
  #pragma unroll 4
  for (int i = 0; i < 53; ++i){
    const int e = i*64 + lane;            // e in [0, 3392)
    const int c = e/136, t = e - c*136;
    const float* gp = S + (size_t)(64+t)*NA + 8*c;
    float4 f0 = *(const float4*)gp, f1 = *(const float4*)(gp + 4);
    uv4 w;
    w.x = pk_f16(f0.x,f0.y); w.y = pk_f16(f0.z,f0.w);
    w.z = pk_f16(f1.x,f1.y); w.w = pk_f16(f1.z,f1.w);
    *(uv4*)(lds_mat + c*544 + 4*t) = w;
  }
  if (has3){                              // tail entries 3392..3399 (c=24)
    const int e = 3392 + lane;
    const int c = e/136, t = e - c*136;
    const float* gp = S + (size_t)(64+t)*NA + 8*c;
    float4 f0 = *(const float4*)gp, f1 = *(const float4*)(gp + 4);
    uv4 w;
    w.x = pk_f16(f0.x,f0.y); w.y = pk_f16(f0.z,f0.w);
    w.z = pk_f16(f1.x,f1.y); w.w = pk_f16(f1.z,f1.w);
    *(uv4*)(lds_mat + c*544 + 4*t) = w;
  }

  float sd[4];
  sd[0] = S[(size_t)lane*201];
  sd[1] = S[(size_t)(64+lane)*201];
  sd[2] = S[(size_t)(128+lane)*201];
  sd[3] = has3 ? S[(size_t)(192+lane)*201] : 1.f;

  // ---- softmax -> b (output 2); clamp+renorm -> b_ (register-only) ----
  float mx = wave_allmax(fmaxf(fmaxf(lg[0],lg[1]), fmaxf(lg[2],lg[3])));
  float ex[4];
  #pragma unroll
  for (int i = 0; i < 4; ++i) ex[i] = expf(lg[i] - mx);   // ex[3]=0 if !has3
  float es = wave_allsum(((ex[0]+ex[1]) + (ex[2]+ex[3])));
  float bsoft[4], bcl[4];
  #pragma unroll
  for (int i = 0; i < 4; ++i) bsoft[i] = ex[i]/es;
  float* outb = out + (size_t)B_SAMPLES*NA + (size_t)s*NA;
  outb[lane] = bsoft[0]; outb[lane+64] = bsoft[1]; outb[lane+128] = bsoft[2];
  if (has3) outb[192+lane] = bsoft[3];
  bcl[0] = fmaxf(bsoft[0], B_MIN_C); bcl[1] = fmaxf(bsoft[1], B_MIN_C);
  bcl[2] = fmaxf(bsoft[2], B_MIN_C);
  bcl[3] = has3 ? fmaxf(bsoft[3], B_MIN_C) : 0.f;
  float bs = wave_allsum((bcl[0]+bcl[1]) + (bcl[2]+bcl[3]));
  float b_[4];
  #pragma unroll
  for (int i = 0; i < 4; ++i) b_[i] = bcl[i]/bs;          // b_[3]=0 if !has3

  put_ph(phs, lane,      b_[0]);
  put_ph(phs, lane+64,   b_[1]);
  put_ph(phs, lane+128,  b_[2]);
  if (has3) put_ph(phs, 192+lane, b_[3]);

  // ---- y0 = bc / sqrt(bc^T S bc) ----
  float y[4], q[4];
  __syncthreads();                        // mat + ph visible
  mv_f16(mregA, lds_mat, ph, lane, l8, q);
  float quad = wave_allsum(fmaf(b_[0],q[0], fmaf(b_[1],q[1],
                           fmaf(b_[2],q[2], b_[3]*q[3]))));
  float rq0 = 1.f/sqrtf(quad);
  y[0] = b_[0]*rq0; y[1] = b_[1]*rq0; y[2] = b_[2]*rq0;
  y[3] = has3 ? b_[3]*rq0 : 1.f;          // masked lanes keep benign y=1
  yv[lane] = y[0]; yv[lane+64] = y[1]; yv[lane+128] = y[2];
  if (has3) yv[192+lane] = y[3];

  // ---- damped inexact Newton (classic PCG inner solver, wave-local) ----
  float gg0 = 1.f;
  bool  ph1done = false;
  int   nexact  = 0;
  for (int it = 0; it < N_PH1 + N_REFINE; ++it){
    if (nexact >= N_REFINE) break;
    const bool exact = ph1done;
    if (exact) ++nexact;

    __syncthreads();                      // yv current
    if (exact){
      mv_exact(S, yv, lane, l8, q);       // exact f32 gradient (once/sample)
    } else {
      mv_f32h(mregA, lds_mat, yv, lane, l8, q);
    }

    // --- Newton init ---
    float g[4], d[4], mi[4];
    #pragma unroll
    for (int i = 0; i < 4; ++i){
      g[i]  = q[i] - b_[i]/y[i];          // masked i=3: b=0,y=1 -> finite
      d[i]  = b_[i]/(y[i]*y[i]);
      mi[i] = 1.f/(sd[i] + d[i]);
    }
    float gg = wave_allsum((g[0]*g[0] + g[1]*g[1]) + (g[2]*g[2]
                           + (has3 ? g[3]*g[3] : 0.f)));
    float rz = wave_allsum((g[0]*g[0]*mi[0] + g[1]*g[1]*mi[1])
                           + (g[2]*g[2]*mi[2] + (has3 ? g[3]*g[3]*mi[3] : 0.f)));
    if (it == 0) gg0 = fmaxf(gg, 1e-30f);
    float tol2 = exact ? TOL2_LO
                       : fminf(TOL2_HI, fmaxf(TOL2_P1, 4.f * (gg / gg0)));

    if (gg > 1e-24f){
      const float cinv = rsqrtf(gg);
      const float csc  = sqrtf(gg);
      float r_[4], z[4], pj[4], dy[4];
      #pragma unroll
      for (int i = 0; i < 4; ++i){
        r_[i] = -g[i]*cinv;
        z[i]  = mi[i]*r_[i];
        if (i == 3) z[3] = has3 ? z[3] : 0.f;   // keep masked pj chain at 0
        pj[i] = z[i];
        dy[i] = 0.f;
      }
      put_ph(phs, lane,     pj[0]);
      put_ph(phs, lane+64,  pj[1]);
      put_ph(phs, lane+128, pj[2]);
      if (has3) put_ph(phs, 192+lane, pj[3]);
      rz = rz * cinv * cinv;
      const float rz0 = rz;

      for (int j = 0; j < CG_MAX; ++j){
        __syncthreads();                  // ph visible (single wave: ~waitcnt)
        float qp[4];
        mv_f16(mregA, lds_mat, ph, lane, l8, qp);
        float qf[4], u[4];
        #pragma unroll
        for (int i = 0; i < 4; ++i){
          qf[i] = fmaf(d[i], pj[i], qp[i]);
          u[i]  = mi[i]*qf[i];
        }
        u[3] = has3 ? u[3] : 0.f;
        float cpq = wave_allsum((pj[0]*qf[0] + pj[1]*qf[1])
                              + (pj[2]*qf[2] + pj[3]*qf[3]));   // pj[3]=0 masked
        float crq = wave_allsum((r_[0]*u[0] + r_[1]*u[1])
                              + (r_[2]*u[2] + r_[3]*u[3]));
        float cqq = wave_allsum((qf[0]*u[0] + qf[1]*u[1])
                              + (qf[2]*u[2] + qf[3]*u[3]));
        float alpha = rz / cpq;
        float rznew = fmaxf(fmaf(alpha*alpha, cqq, fmaf(-2.f*alpha, crq, rz)), 0.f);
        #pragma unroll
        for (int i = 0; i < 4; ++i){
          dy[i] = fmaf( alpha, pj[i], dy[i]);
          r_[i] = fmaf(-alpha, qf[i], r_[i]);
          z[i]  = mi[i]*r_[i];
        }
        z[3] = has3 ? z[3] : 0.f;
        bool brk = (rznew <= tol2 * rz0) || (j == CG_MAX - 1);
        if (!brk){
          float beta = rznew / rz;
          #pragma unroll
          for (int i = 0; i < 4; ++i) pj[i] = fmaf(beta, pj[i], z[i]);
          put_ph(phs, lane,     pj[0]);
          put_ph(phs, lane+64,  pj[1]);
          put_ph(phs, lane+128, pj[2]);
          if (has3) put_ph(phs, 192+lane, pj[3]);
        }
        rz = rznew;
        if (brk) break;
      }

      // --- unscale dy; damped step keeping y > 0 (reference semantics) ---
      float ratio = 1e30f;
      #pragma unroll
      for (int i = 0; i < 4; ++i){
        dy[i] *= csc;                     // dy[3]=0 for masked lanes
        ratio = fminf(ratio, (dy[i] < 0.f) ? (-y[i]/dy[i]) : 1e30f);
      }
      float mr = wave_allmin(ratio);
      float t = fminf(1.f, 0.9f * mr);
      #pragma unroll
      for (int i = 0; i < 4; ++i) y[i] = fmaxf(fmaf(t, dy[i], y[i]), 1e-12f);
      yv[lane] = y[0]; yv[lane+64] = y[1]; yv[lane+128] = y[2];
      if (has3) yv[192+lane] = y[3];
    }

    if (!exact && (gg <= 1e-8f * gg0 || it + 1 >= N_PH1)) ph1done = true;
  }

  // ---- z = y / sum(y) (output 1) ----
  float ys = wave_allsum((y[0] + y[1]) + (y[2] + (has3 ? y[3] : 0.f)));
  float* outz = out + (size_t)s*NA;
  outz[lane] = y[0]/ys; outz[lane+64] = y[1]/ys; outz[lane+128] = y[2]/ys;
  if (has3) outz[192+lane] = y[3]/ys;
}

extern "C" void kernel_launch(void* const* d_in, const int* in_sizes, int n_in,
                              void* d_out, int out_size, void* d_ws, size_t ws_size,
                              hipStream_t stream) {
  const float* x     = (const float*)d_in[0];
  const float* Sigma = (const float*)d_in[1];
  const float* W1    = (const float*)d_in[2];
  const float* b1    = (const float*)d_in[3];
  const float* W2    = (const float*)d_in[4];
  const float* b2    = (const float*)d_in[5];
  float* out = (float*)d_out;
  hipLaunchKernelGGL(rb_kernel, dim3(B_SAMPLES), dim3(NTHREADS), 0, stream,
                     x, Sigma, W1, b1, W2, b2, out);
}

// Round 7
// 347.223 us; speedup vs baseline: 1.6279x; 1.1696x over previous
//
#include <hip/hip_runtime.h>
#include <math.h>

#define NF        128
#define H_DIM     256
#define NA        200
#define B_SAMPLES 512
#define ALPHA_LR  0.01f
#define B_MIN_C   1e-4f

#define NTHREADS  256               // 4 waves: thread t owns full row t (t<200)
#define ROWS_PER_WAVE 50            // exact-path: 4 waves x 50 rows

#define N_PH1     10
#define N_REFINE  1
#define CG_MAX    32                // R7: tail cap (was 40; rarely hit w/ loose tol)
#define TOL2_LO   4e-4f             // refinement CG tolerance (UNCHANGED: accuracy)
#define TOL2_P1   4e-3f             // R7: phase-1 CG tolerance floor (was 1e-3)
#define TOL2_HI   6e-2f             // R7: phase-1 CG tolerance cap (was 2.5e-2)
#define P1_FACT   8.f               // R7: adaptive factor (was 4)
#define P1_EXIT   1e-7f             // R7: phase-1 Newton early-exit (was 1e-8)

typedef _Float16 h2_t __attribute__((ext_vector_type(2)));
typedef unsigned uv4  __attribute__((ext_vector_type(4)));

__device__ __forceinline__ h2_t as_h2(unsigned u){
  union { unsigned u; h2_t h; } c; c.u = u; return c.h;
}
__device__ __forceinline__ unsigned pk_f16(float a, float b){
#if __has_builtin(__builtin_amdgcn_cvt_pkrtz)
  union { decltype(__builtin_amdgcn_cvt_pkrtz(0.f, 0.f)) h; unsigned u; } c;
  c.h = __builtin_amdgcn_cvt_pkrtz(a, b);
  return c.u;
#else
  union { h2_t h; unsigned u; } c;
  c.h = (h2_t){ (_Float16)a, (_Float16)b };
  return c.u;
#endif
}
__device__ __forceinline__ float fdot2(unsigned m, unsigned v, float acc){
#if __has_builtin(__builtin_amdgcn_fdot2)
  return __builtin_amdgcn_fdot2(as_h2(m), as_h2(v), acc, false);
#else
  h2_t a = as_h2(m), b = as_h2(v);
  return fmaf((float)a.y, (float)b.y, fmaf((float)a.x, (float)b.x, acc));
#endif
}

// ---------------- DPP wave-64 reductions (result valid in lane 63) --------
__device__ __forceinline__ float dpp_wave_sum(float v){
  v += __int_as_float(__builtin_amdgcn_update_dpp(0, __float_as_int(v), 0x111, 0xf, 0xf, false));
  v += __int_as_float(__builtin_amdgcn_update_dpp(0, __float_as_int(v), 0x112, 0xf, 0xf, false));
  v += __int_as_float(__builtin_amdgcn_update_dpp(0, __float_as_int(v), 0x114, 0xf, 0xf, false));
  v += __int_as_float(__builtin_amdgcn_update_dpp(0, __float_as_int(v), 0x118, 0xf, 0xf, false));
  v += __int_as_float(__builtin_amdgcn_update_dpp(0, __float_as_int(v), 0x142, 0xa, 0xf, false));
  v += __int_as_float(__builtin_amdgcn_update_dpp(0, __float_as_int(v), 0x143, 0xc, 0xf, false));
  return v;
}
__device__ __forceinline__ float dpp_wave_min(float v){
  const int PINF = 0x7f800000;
  v = fminf(v, __int_as_float(__builtin_amdgcn_update_dpp(PINF, __float_as_int(v), 0x111, 0xf, 0xf, false)));
  v = fminf(v, __int_as_float(__builtin_amdgcn_update_dpp(PINF, __float_as_int(v), 0x112, 0xf, 0xf, false)));
  v = fminf(v, __int_as_float(__builtin_amdgcn_update_dpp(PINF, __float_as_int(v), 0x114, 0xf, 0xf, false)));
  v = fminf(v, __int_as_float(__builtin_amdgcn_update_dpp(PINF, __float_as_int(v), 0x118, 0xf, 0xf, false)));
  v = fminf(v, __int_as_float(__builtin_amdgcn_update_dpp(PINF, __float_as_int(v), 0x142, 0xa, 0xf, false)));
  v = fminf(v, __int_as_float(__builtin_amdgcn_update_dpp(PINF, __float_as_int(v), 0x143, 0xc, 0xf, false)));
  return v;
}
__device__ __forceinline__ float dpp_wave_max(float v){
  const int NINF = 0xff800000;
  v = fmaxf(v, __int_as_float(__builtin_amdgcn_update_dpp(NINF, __float_as_int(v), 0x111, 0xf, 0xf, false)));
  v = fmaxf(v, __int_as_float(__builtin_amdgcn_update_dpp(NINF, __float_as_int(v), 0x112, 0xf, 0xf, false)));
  v = fmaxf(v, __int_as_float(__builtin_amdgcn_update_dpp(NINF, __float_as_int(v), 0x114, 0xf, 0xf, false)));
  v = fmaxf(v, __int_as_float(__builtin_amdgcn_update_dpp(NINF, __float_as_int(v), 0x118, 0xf, 0xf, false)));
  v = fmaxf(v, __int_as_float(__builtin_amdgcn_update_dpp(NINF, __float_as_int(v), 0x142, 0xa, 0xf, false)));
  v = fmaxf(v, __int_as_float(__builtin_amdgcn_update_dpp(NINF, __float_as_int(v), 0x143, 0xc, 0xf, false)));
  return v;
}
// block reductions over 4 waves (prologue only)
__device__ __forceinline__ float block_sum4(float v, float* red, int tid){
  __syncthreads();
  v = dpp_wave_sum(v);
  if ((tid & 63) == 63) red[tid >> 6] = v;
  __syncthreads();
  return (red[0] + red[1]) + (red[2] + red[3]);
}
__device__ __forceinline__ float block_max4(float v, float* red, int tid){
  __syncthreads();
  v = dpp_wave_max(v);
  if ((tid & 63) == 63) red[tid >> 6] = v;
  __syncthreads();
  return fmaxf(fmaxf(red[0], red[1]), fmaxf(red[2], red[3]));
}

// owner writes its f16 vector entry (rows 0..199 contiguous)
__device__ __forceinline__ void put_ph(unsigned short* phs, int row, float v){
  phs[row] = (unsigned short)(pk_f16(v, 0.f) & 0xffffu);
}

// packed-f16 full-row matvec: 100 dwords from VGPRs, vector broadcast from LDS
__device__ __forceinline__ float mv_dot2(const unsigned* mreg,
                                         const unsigned* __restrict__ ph){
  const uv4* v4 = (const uv4*)ph;
  float a0=0.f, a1=0.f, a2=0.f, a3=0.f;
  #pragma unroll
  for (int k = 0; k < 25; ++k){
    uv4 vv = v4[k];
    a0 = fdot2(mreg[4*k+0], vv.x, a0);
    a1 = fdot2(mreg[4*k+1], vv.y, a1);
    a2 = fdot2(mreg[4*k+2], vv.z, a2);
    a3 = fdot2(mreg[4*k+3], vv.w, a3);
  }
  return (a0 + a1) + (a2 + a3);
}

// f16-matrix x fp32-vector (phase-1 gradient: exact fixed point of f16 system)
__device__ __forceinline__ float mv_f32v(const unsigned* mreg,
                                         const float* __restrict__ vv){
  const float4* v4 = (const float4*)vv;
  float a0=0.f, a1=0.f, a2=0.f, a3=0.f;
  #pragma unroll
  for (int k = 0; k < 25; ++k){
    float4 va = v4[2*k], vb = v4[2*k+1];
    h2_t m0 = as_h2(mreg[4*k+0]), m1 = as_h2(mreg[4*k+1]);
    h2_t m2 = as_h2(mreg[4*k+2]), m3 = as_h2(mreg[4*k+3]);
    a0 = fmaf((float)m0.x, va.x, a0); a1 = fmaf((float)m0.y, va.y, a1);
    a2 = fmaf((float)m1.x, va.z, a2); a3 = fmaf((float)m1.y, va.w, a3);
    a0 = fmaf((float)m2.x, vb.x, a0); a1 = fmaf((float)m2.y, vb.y, a1);
    a2 = fmaf((float)m3.x, vb.z, a2); a3 = fmaf((float)m3.y, vb.w, a3);
  }
  return (a0 + a1) + (a2 + a3);
}

extern "C" __global__ __launch_bounds__(NTHREADS)   // NOTE: no 2nd arg — any
// waves-per-EU hint clamps the allocator and spills mreg (prior evidence).
void rb_kernel(const float* __restrict__ x,  const float* __restrict__ Sigma,
               const float* __restrict__ W1, const float* __restrict__ b1,
               const float* __restrict__ W2, const float* __restrict__ b2,
               float* __restrict__ out) {
  __shared__ __align__(16) unsigned ph[100];          // packed f16 vector (200 h)
  __shared__ __align__(16) float yv[NA];
  __shared__ __align__(16) float partial[NA];
  __shared__ float xs[NF];
  __shared__ float hs[H_DIM];
  __shared__ __align__(16) float4 red4[4];            // fused CG reduction slots
  __shared__ float redD[4], red8[4];

  const int tid  = threadIdx.x;
  const int s    = blockIdx.x;
  const bool act = tid < NA;                          // thread t owns row t
  const int row  = tid;
  const float* S = Sigma + (size_t)s * NA * NA;
  unsigned short* phs = (unsigned short*)ph;

  if (tid < NF) xs[tid] = x[s * NF + tid];
  float sd = act ? S[(size_t)row * NA + row] : 0.f;

  // ---- stage Sigma row (packed f16): 100 dwords -> VGPRs ----
  unsigned mreg[100];
  if (act){
    const float4* rowp = (const float4*)(S + (size_t)row * NA);
    #pragma unroll
    for (int k = 0; k < 50; ++k){
      float4 w = rowp[k];
      mreg[2*k]   = pk_f16(w.x, w.y);
      mreg[2*k+1] = pk_f16(w.z, w.w);
    }
  }

  // ---- MLP ----
  __syncthreads();                        // xs visible
  {
    const float* w = W1 + tid * NF;       // tid < 256 == H_DIM
    float acc = b1[tid];
    #pragma unroll 8
    for (int j = 0; j < NF; ++j) acc = fmaf(w[j], xs[j], acc);
    hs[tid] = (acc >= 0.f) ? acc : ALPHA_LR * acc;
  }
  __syncthreads();
  float logit = -INFINITY;
  if (act){
    const float* w = W2 + row * H_DIM;
    float acc = b2[row];
    #pragma unroll 8
    for (int j = 0; j < H_DIM; ++j) acc = fmaf(w[j], hs[j], acc);
    logit = acc;
  }

  // ---- softmax -> b (output 2); clamp+renorm -> b_ (local, row==tid) ----
  float mx = block_max4(logit, red8, tid);
  float e  = act ? expf(logit - mx) : 0.f;
  float es = block_sum4(e, red8, tid);
  float bsoft = e / es;
  if (act) out[(size_t)B_SAMPLES * NA + (size_t)s * NA + row] = bsoft;
  float bcl = fmaxf(bsoft, B_MIN_C);
  float bs  = block_sum4(act ? bcl : 0.f, red8, tid);

  float b_ = 0.f, y = 0.f;
  if (act){ b_ = bcl / bs; put_ph(phs, row, b_); }

  // ---- y0 = bc / sqrt(bc^T S bc) ----
  __syncthreads();                               // ph visible
  {
    float acc = act ? mv_dot2(mreg, ph) : 0.f;
    float wq  = dpp_wave_sum(act ? b_ * acc : 0.f);
    if ((tid & 63) == 63) red4[tid >> 6] = make_float4(wq, 0.f, 0.f, 0.f);
    __syncthreads();
    float quad = (red4[0].x + red4[1].x) + (red4[2].x + red4[3].x);
    if (act){ y = b_ / sqrtf(quad); yv[row] = y; }
  }

  // ---- damped inexact Newton ----
  float gg0 = 1.f;
  bool  ph1done = false;
  int   nexact  = 0;
  for (int it = 0; it < N_PH1 + N_REFINE; ++it){
    if (nexact >= N_REFINE) break;
    const bool exact = ph1done;
    if (exact) ++nexact;

    // --- gradient matvec q = (S y)_row (fp32 y, f16 or exact matrix) ---
    float q = 0.f;
    if (exact){
      __syncthreads();                           // yv visible, partial free
      int lane = tid & 63, wid = tid >> 6;
      int r0 = wid * ROWS_PER_WAVE;
      for (int rr = r0; rr < r0 + ROWS_PER_WAVE; ++rr){
        const float* rowp = S + (size_t)rr * NA;
        float a = rowp[lane]*yv[lane] + rowp[lane+64]*yv[lane+64]
                + rowp[lane+128]*yv[lane+128];
        if (lane < NA - 192) a += rowp[lane+192]*yv[lane+192];
        a = dpp_wave_sum(a);
        if (lane == 63) partial[rr] = a;
      }
      __syncthreads();
      if (act) q = partial[row];
    } else {
      __syncthreads();                           // yv visible
      q = act ? mv_f32v(mreg, yv) : 0.f;
    }

    // --- Newton init; reduce gg and rz together ---
    float g=0.f, d=0.f, mi=0.f;
    if (act){
      g  = q - b_ / y;
      d  = b_ / (y * y);
      mi = 1.f / (sd + d);
    }
    float wg = dpp_wave_sum(act ? g * g : 0.f);
    float wz = dpp_wave_sum(act ? g * g * mi : 0.f);   // rz = g^T M^-1 g
    if ((tid & 63) == 63) red4[tid >> 6] = make_float4(wg, wz, 0.f, 0.f);
    __syncthreads();
    float4 t0 = red4[0], t1 = red4[1], t2 = red4[2], t3 = red4[3];
    float gg = (t0.x + t1.x) + (t2.x + t3.x);
    float rz = (t0.y + t1.y) + (t2.y + t3.y);
    if (it == 0) gg0 = fmaxf(gg, 1e-30f);
    float tol2 = exact ? TOL2_LO
                       : fminf(TOL2_HI, fmaxf(TOL2_P1, P1_FACT * (gg / gg0)));

    if (gg > 1e-24f){
      // --- scale CG system by 1/||g|| so packed-f16 p never underflows ---
      const float cinv = rsqrtf(gg);
      const float csc  = sqrtf(gg);
      float r=0.f, z=0.f, dy=0.f, pj=0.f;
      if (act){
        r  = -g * cinv;
        z  = mi * r;
        pj = z;
        put_ph(phs, row, pj);
      }
      rz = rz * cinv * cinv;

      // --- Jacobi-PCG, fused single reduction (pq, rq, qq in one float4) ---
      const float rz0 = rz;
      for (int j = 0; j < CG_MAX; ++j){
        __syncthreads();                         // B1: ph visible, red4 reuse safe
        float qp = act ? mv_dot2(mreg, ph) : 0.f;
        float qf=0.f, cpq=0.f, crq=0.f, cqq=0.f;
        if (act){
          qf = qp + d * pj;
          float u = mi * qf;
          cpq = pj * qf; crq = r * u; cqq = qf * u;
        }
        cpq = dpp_wave_sum(cpq); crq = dpp_wave_sum(crq); cqq = dpp_wave_sum(cqq);
        if ((tid & 63) == 63) red4[tid >> 6] = make_float4(cpq, crq, cqq, 0.f);
        __syncthreads();                         // B2
        float4 u0 = red4[0], u1 = red4[1], u2 = red4[2], u3 = red4[3];
        float pq = (u0.x + u1.x) + (u2.x + u3.x);
        float rq = (u0.y + u1.y) + (u2.y + u3.y);
        float qq = (u0.z + u1.z) + (u2.z + u3.z);
        float alpha = rz / pq;
        float rznew = fmaxf(fmaf(alpha*alpha, qq, fmaf(-2.f*alpha, rq, rz)), 0.f);
        if (act){
          dy = fmaf(alpha, pj, dy);
          r  = fmaf(-alpha, qf, r);
          z  = mi * r;
        }
        bool brk = (rznew <= tol2 * rz0) || (j == CG_MAX - 1);
        if (!brk){
          float beta = rznew / rz;
          if (act){ pj = fmaf(beta, pj, z); put_ph(phs, row, pj); }
        }
        rz = rznew;
        if (brk) break;
      }

      // --- unscale dy; damped step keeping y > 0 (reference semantics) ---
      if (act) dy *= csc;
      float ratio = (act && dy < 0.f) ? (-y / dy) : 1e30f;
      float wmn = dpp_wave_min(ratio);
      if ((tid & 63) == 63) redD[tid >> 6] = wmn;
      __syncthreads();
      float mr = fminf(fminf(redD[0], redD[1]), fminf(redD[2], redD[3]));
      float t = fminf(1.f, 0.9f * mr);
      if (act){
        y = fmaxf(fmaf(t, dy, y), 1e-12f);
        yv[row] = y;
        put_ph(phs, row, y);                     // repack y for next f16 use
      }
    }

    if (!exact && (gg <= P1_EXIT * gg0 || it + 1 >= N_PH1)) ph1done = true;
  }

  // ---- z = y / sum(y) (output 1) ----
  float wy = dpp_wave_sum(act ? y : 0.f);
  if ((tid & 63) == 63) red4[tid >> 6] = make_float4(wy, 0.f, 0.f, 0.f);
  __syncthreads();
  float ys = (red4[0].x + red4[1].x) + (red4[2].x + red4[3].x);
  if (act) out[(size_t)s * NA + row] = y / ys;
}

extern "C" void kernel_launch(void* const* d_in, const int* in_sizes, int n_in,
                              void* d_out, int out_size, void* d_ws, size_t ws_size,
                              hipStream_t stream) {
  const float* x     = (const float*)d_in[0];
  const float* Sigma = (const float*)d_in[1];
  const float* W1    = (const float*)d_in[2];
  const float* b1    = (const float*)d_in[3];
  const float* W2    = (const float*)d_in[4];
  const float* b2    = (const float*)d_in[5];
  float* out = (float*)d_out;
  hipLaunchKernelGGL(rb_kernel, dim3(B_SAMPLES), dim3(NTHREADS), 0, stream,
                     x, Sigma, W1, b1, W2, b2, out);
}

// Round 8
// 346.096 us; speedup vs baseline: 1.6332x; 1.0033x over previous
//
#include <hip/hip_runtime.h>
#include <math.h>

#define NF        128
#define H_DIM     256
#define NA        200
#define B_SAMPLES 512
#define ALPHA_LR  0.01f
#define B_MIN_C   1e-4f

#define NTHREADS  256               // 4 waves: thread t owns full row t (t<200)
#define ROWS_PER_WAVE 50            // exact-path: 4 waves x 50 rows

#define N_PH1     10
#define N_REFINE  1
#define CG_MAX    32
#define TOL2_LO   4e-4f             // refinement CG tolerance (accuracy anchor)
#define TOL2_P1   4e-3f             // phase-1 CG tolerance floor
#define TOL2_HI   6e-2f             // phase-1 CG tolerance cap
#define P1_FACT   8.f               // adaptive factor
#define P1_EXIT   1e-7f             // phase-1 Newton early-exit

typedef _Float16 h2_t __attribute__((ext_vector_type(2)));
typedef unsigned uv4  __attribute__((ext_vector_type(4)));

__device__ __forceinline__ h2_t as_h2(unsigned u){
  union { unsigned u; h2_t h; } c; c.u = u; return c.h;
}
__device__ __forceinline__ unsigned pk_f16(float a, float b){
#if __has_builtin(__builtin_amdgcn_cvt_pkrtz)
  union { decltype(__builtin_amdgcn_cvt_pkrtz(0.f, 0.f)) h; unsigned u; } c;
  c.h = __builtin_amdgcn_cvt_pkrtz(a, b);
  return c.u;
#else
  union { h2_t h; unsigned u; } c;
  c.h = (h2_t){ (_Float16)a, (_Float16)b };
  return c.u;
#endif
}
__device__ __forceinline__ float fdot2(unsigned m, unsigned v, float acc){
#if __has_builtin(__builtin_amdgcn_fdot2)
  return __builtin_amdgcn_fdot2(as_h2(m), as_h2(v), acc, false);
#else
  h2_t a = as_h2(m), b = as_h2(v);
  return fmaf((float)a.y, (float)b.y, fmaf((float)a.x, (float)b.x, acc));
#endif
}
// fast reciprocal (v_rcp_f32, ~1e-7 rel) for loop-carried scalar chain
__device__ __forceinline__ float fast_rcp(float x){
#if __has_builtin(__builtin_amdgcn_rcpf)
  return __builtin_amdgcn_rcpf(x);
#else
  return 1.f / x;
#endif
}

// ---------------- DPP wave-64 reductions (result valid in lane 63) --------
__device__ __forceinline__ float dpp_wave_sum(float v){
  v += __int_as_float(__builtin_amdgcn_update_dpp(0, __float_as_int(v), 0x111, 0xf, 0xf, false));
  v += __int_as_float(__builtin_amdgcn_update_dpp(0, __float_as_int(v), 0x112, 0xf, 0xf, false));
  v += __int_as_float(__builtin_amdgcn_update_dpp(0, __float_as_int(v), 0x114, 0xf, 0xf, false));
  v += __int_as_float(__builtin_amdgcn_update_dpp(0, __float_as_int(v), 0x118, 0xf, 0xf, false));
  v += __int_as_float(__builtin_amdgcn_update_dpp(0, __float_as_int(v), 0x142, 0xa, 0xf, false));
  v += __int_as_float(__builtin_amdgcn_update_dpp(0, __float_as_int(v), 0x143, 0xc, 0xf, false));
  return v;
}
__device__ __forceinline__ float dpp_wave_min(float v){
  const int PINF = 0x7f800000;
  v = fminf(v, __int_as_float(__builtin_amdgcn_update_dpp(PINF, __float_as_int(v), 0x111, 0xf, 0xf, false)));
  v = fminf(v, __int_as_float(__builtin_amdgcn_update_dpp(PINF, __float_as_int(v), 0x112, 0xf, 0xf, false)));
  v = fminf(v, __int_as_float(__builtin_amdgcn_update_dpp(PINF, __float_as_int(v), 0x114, 0xf, 0xf, false)));
  v = fminf(v, __int_as_float(__builtin_amdgcn_update_dpp(PINF, __float_as_int(v), 0x118, 0xf, 0xf, false)));
  v = fminf(v, __int_as_float(__builtin_amdgcn_update_dpp(PINF, __float_as_int(v), 0x142, 0xa, 0xf, false)));
  v = fminf(v, __int_as_float(__builtin_amdgcn_update_dpp(PINF, __float_as_int(v), 0x143, 0xc, 0xf, false)));
  return v;
}
__device__ __forceinline__ float dpp_wave_max(float v){
  const int NINF = 0xff800000;
  v = fmaxf(v, __int_as_float(__builtin_amdgcn_update_dpp(NINF, __float_as_int(v), 0x111, 0xf, 0xf, false)));
  v = fmaxf(v, __int_as_float(__builtin_amdgcn_update_dpp(NINF, __float_as_int(v), 0x112, 0xf, 0xf, false)));
  v = fmaxf(v, __int_as_float(__builtin_amdgcn_update_dpp(NINF, __float_as_int(v), 0x114, 0xf, 0xf, false)));
  v = fmaxf(v, __int_as_float(__builtin_amdgcn_update_dpp(NINF, __float_as_int(v), 0x118, 0xf, 0xf, false)));
  v = fmaxf(v, __int_as_float(__builtin_amdgcn_update_dpp(NINF, __float_as_int(v), 0x142, 0xa, 0xf, false)));
  v = fmaxf(v, __int_as_float(__builtin_amdgcn_update_dpp(NINF, __float_as_int(v), 0x143, 0xc, 0xf, false)));
  return v;
}
// block reductions over 4 waves (prologue only)
__device__ __forceinline__ float block_sum4(float v, float* red, int tid){
  __syncthreads();
  v = dpp_wave_sum(v);
  if ((tid & 63) == 63) red[tid >> 6] = v;
  __syncthreads();
  return (red[0] + red[1]) + (red[2] + red[3]);
}
__device__ __forceinline__ float block_max4(float v, float* red, int tid){
  __syncthreads();
  v = dpp_wave_max(v);
  if ((tid & 63) == 63) red[tid >> 6] = v;
  __syncthreads();
  return fmaxf(fmaxf(red[0], red[1]), fmaxf(red[2], red[3]));
}

// owner writes its f16 vector entry (rows 0..199 contiguous)
__device__ __forceinline__ void put_ph(unsigned short* phs, int row, float v){
  phs[row] = (unsigned short)(pk_f16(v, 0.f) & 0xffffu);
}

// packed-f16 full-row matvec: 100 dwords from VGPRs.
// R8: prefetch ALL 25 p-quads first (one LDS-latency exposure, not five);
// launch_bounds(.,2) raises the VGPR cap to 256 so this stays in registers.
__device__ __forceinline__ float mv_dot2(const unsigned* mreg,
                                         const unsigned* __restrict__ ph){
  const uv4* v4 = (const uv4*)ph;
  uv4 pv[25];
  #pragma unroll
  for (int k = 0; k < 25; ++k) pv[k] = v4[k];
  float a0=0.f, a1=0.f, a2=0.f, a3=0.f;
  #pragma unroll
  for (int k = 0; k < 25; ++k){
    a0 = fdot2(mreg[4*k+0], pv[k].x, a0);
    a1 = fdot2(mreg[4*k+1], pv[k].y, a1);
    a2 = fdot2(mreg[4*k+2], pv[k].z, a2);
    a3 = fdot2(mreg[4*k+3], pv[k].w, a3);
  }
  return (a0 + a1) + (a2 + a3);
}

// f16-matrix x fp32-vector (phase-1 gradient: exact fixed point of f16 system)
__device__ __forceinline__ float mv_f32v(const unsigned* mreg,
                                         const float* __restrict__ vv){
  const float4* v4 = (const float4*)vv;
  float a0=0.f, a1=0.f, a2=0.f, a3=0.f;
  #pragma unroll
  for (int k = 0; k < 25; ++k){
    float4 va = v4[2*k], vb = v4[2*k+1];
    h2_t m0 = as_h2(mreg[4*k+0]), m1 = as_h2(mreg[4*k+1]);
    h2_t m2 = as_h2(mreg[4*k+2]), m3 = as_h2(mreg[4*k+3]);
    a0 = fmaf((float)m0.x, va.x, a0); a1 = fmaf((float)m0.y, va.y, a1);
    a2 = fmaf((float)m1.x, va.z, a2); a3 = fmaf((float)m1.y, va.w, a3);
    a0 = fmaf((float)m2.x, vb.x, a0); a1 = fmaf((float)m2.y, vb.y, a1);
    a2 = fmaf((float)m3.x, vb.z, a2); a3 = fmaf((float)m3.y, vb.w, a3);
  }
  return (a0 + a1) + (a2 + a3);
}

// launch_bounds(256, 2): min-waves/EU = 2 == exactly our residency target
// (2 blocks/CU x 4 waves = 2 waves/SIMD), raising the allocator VGPR cap to
// 256 (at 144 the mv_dot2 p-reads serialized 5-deep). A LARGER waves hint
// (4+) clamps to <=128 VGPRs and spills mreg — do not raise it.
extern "C" __global__ __launch_bounds__(NTHREADS, 2)
void rb_kernel(const float* __restrict__ x,  const float* __restrict__ Sigma,
               const float* __restrict__ W1, const float* __restrict__ b1,
               const float* __restrict__ W2, const float* __restrict__ b2,
               float* __restrict__ out) {
  __shared__ __align__(16) unsigned ph[100];          // packed f16 vector (200 h)
  __shared__ __align__(16) float yv[NA];
  __shared__ __align__(16) float partial[NA];
  __shared__ float xs[NF];
  __shared__ float hs[H_DIM];
  __shared__ __align__(16) float4 red4[4];            // fused CG reduction slots
  __shared__ float redD[4], red8[4];

  const int tid  = threadIdx.x;
  const int s    = blockIdx.x;
  const bool act = tid < NA;                          // thread t owns row t
  const int row  = tid;
  const float* S = Sigma + (size_t)s * NA * NA;
  unsigned short* phs = (unsigned short*)ph;

  if (tid < NF) xs[tid] = x[s * NF + tid];
  float sd = act ? S[(size_t)row * NA + row] : 0.f;

  // ---- stage Sigma row (packed f16): 100 dwords -> VGPRs ----
  unsigned mreg[100];
  if (act){
    const float4* rowp = (const float4*)(S + (size_t)row * NA);
    #pragma unroll
    for (int k = 0; k < 50; ++k){
      float4 w = rowp[k];
      mreg[2*k]   = pk_f16(w.x, w.y);
      mreg[2*k+1] = pk_f16(w.z, w.w);
    }
  }

  // ---- MLP ----
  __syncthreads();                        // xs visible
  {
    const float* w = W1 + tid * NF;       // tid < 256 == H_DIM
    float acc = b1[tid];
    #pragma unroll 8
    for (int j = 0; j < NF; ++j) acc = fmaf(w[j], xs[j], acc);
    hs[tid] = (acc >= 0.f) ? acc : ALPHA_LR * acc;
  }
  __syncthreads();
  float logit = -INFINITY;
  if (act){
    const float* w = W2 + row * H_DIM;
    float acc = b2[row];
    #pragma unroll 8
    for (int j = 0; j < H_DIM; ++j) acc = fmaf(w[j], hs[j], acc);
    logit = acc;
  }

  // ---- softmax -> b (output 2); clamp+renorm -> b_ (local, row==tid) ----
  float mx = block_max4(logit, red8, tid);
  float e  = act ? expf(logit - mx) : 0.f;
  float es = block_sum4(e, red8, tid);
  float bsoft = e / es;
  if (act) out[(size_t)B_SAMPLES * NA + (size_t)s * NA + row] = bsoft;
  float bcl = fmaxf(bsoft, B_MIN_C);
  float bs  = block_sum4(act ? bcl : 0.f, red8, tid);

  float b_ = 0.f, y = 0.f;
  if (act){ b_ = bcl / bs; put_ph(phs, row, b_); }

  // ---- y0 = bc / sqrt(bc^T S bc) ----
  __syncthreads();                               // ph visible
  {
    float acc = act ? mv_dot2(mreg, ph) : 0.f;
    float wq  = dpp_wave_sum(act ? b_ * acc : 0.f);
    if ((tid & 63) == 63) red4[tid >> 6] = make_float4(wq, 0.f, 0.f, 0.f);
    __syncthreads();
    float quad = (red4[0].x + red4[1].x) + (red4[2].x + red4[3].x);
    if (act){ y = b_ / sqrtf(quad); yv[row] = y; }
  }

  // ---- damped inexact Newton ----
  float gg0 = 1.f;
  bool  ph1done = false;
  int   nexact  = 0;
  for (int it = 0; it < N_PH1 + N_REFINE; ++it){
    if (nexact >= N_REFINE) break;
    const bool exact = ph1done;
    if (exact) ++nexact;

    // --- gradient matvec q = (S y)_row (fp32 y, f16 or exact matrix) ---
    float q = 0.f;
    if (exact){
      __syncthreads();                           // yv visible, partial free
      int lane = tid & 63, wid = tid >> 6;
      int r0 = wid * ROWS_PER_WAVE;
      for (int rr = r0; rr < r0 + ROWS_PER_WAVE; ++rr){
        const float* rowp = S + (size_t)rr * NA;
        float a = rowp[lane]*yv[lane] + rowp[lane+64]*yv[lane+64]
                + rowp[lane+128]*yv[lane+128];
        if (lane < NA - 192) a += rowp[lane+192]*yv[lane+192];
        a = dpp_wave_sum(a);
        if (lane == 63) partial[rr] = a;
      }
      __syncthreads();
      if (act) q = partial[row];
    } else {
      __syncthreads();                           // yv visible
      q = act ? mv_f32v(mreg, yv) : 0.f;
    }

    // --- Newton init; reduce gg and rz together ---
    float g=0.f, d=0.f, mi=0.f;
    if (act){
      float ry = fast_rcp(y);
      g  = q - b_ * ry;
      d  = b_ * ry * ry;
      mi = fast_rcp(sd + d);
    }
    float wg = dpp_wave_sum(act ? g * g : 0.f);
    float wz = dpp_wave_sum(act ? g * g * mi : 0.f);   // rz = g^T M^-1 g
    if ((tid & 63) == 63) red4[tid >> 6] = make_float4(wg, wz, 0.f, 0.f);
    __syncthreads();
    float4 t0 = red4[0], t1 = red4[1], t2 = red4[2], t3 = red4[3];
    float gg = (t0.x + t1.x) + (t2.x + t3.x);
    float rz = (t0.y + t1.y) + (t2.y + t3.y);
    if (it == 0) gg0 = fmaxf(gg, 1e-30f);
    float tol2 = exact ? TOL2_LO
                       : fminf(TOL2_HI, fmaxf(TOL2_P1, P1_FACT * (gg / gg0)));

    if (gg > 1e-24f){
      // --- scale CG system by 1/||g|| so packed-f16 p never underflows ---
      const float cinv = rsqrtf(gg);
      const float csc  = sqrtf(gg);
      float r=0.f, z=0.f, dy=0.f, pj=0.f;
      if (act){
        r  = -g * cinv;
        z  = mi * r;
        pj = z;
        put_ph(phs, row, pj);
      }
      rz = rz * cinv * cinv;

      // --- Jacobi-PCG, fused single reduction (pq, rq, qq in one float4) ---
      const float rz0 = rz;
      for (int j = 0; j < CG_MAX; ++j){
        __syncthreads();                         // B1: ph visible, red4 reuse safe
        float qp = act ? mv_dot2(mreg, ph) : 0.f;
        float qf=0.f, cpq=0.f, crq=0.f, cqq=0.f;
        if (act){
          qf = qp + d * pj;
          float u = mi * qf;
          cpq = pj * qf; crq = r * u; cqq = qf * u;
        }
        cpq = dpp_wave_sum(cpq); crq = dpp_wave_sum(crq); cqq = dpp_wave_sum(cqq);
        if ((tid & 63) == 63) red4[tid >> 6] = make_float4(cpq, crq, cqq, 0.f);
        __syncthreads();                         // B2
        float4 u0 = red4[0], u1 = red4[1], u2 = red4[2], u3 = red4[3];
        float pq = (u0.x + u1.x) + (u2.x + u3.x);
        float rq = (u0.y + u1.y) + (u2.y + u3.y);
        float qq = (u0.z + u1.z) + (u2.z + u3.z);
        float alpha = rz * fast_rcp(pq);
        float rznew = fmaxf(fmaf(alpha*alpha, qq, fmaf(-2.f*alpha, rq, rz)), 0.f);
        if (act){
          dy = fmaf(alpha, pj, dy);
          r  = fmaf(-alpha, qf, r);
          z  = mi * r;
        }
        bool brk = (rznew <= tol2 * rz0) || (j == CG_MAX - 1);
        if (!brk){
          float beta = rznew * fast_rcp(rz);
          if (act){ pj = fmaf(beta, pj, z); put_ph(phs, row, pj); }
        }
        rz = rznew;
        if (brk) break;
      }

      // --- unscale dy; damped step keeping y > 0.
      // Phase-1 uses 0.95 fraction-to-boundary (faster warm-up for the
      // concentrated-b tail); the exact refinement keeps reference 0.9. ---
      if (act) dy *= csc;
      float ratio = (act && dy < 0.f) ? (-y / dy) : 1e30f;
      float wmn = dpp_wave_min(ratio);
      if ((tid & 63) == 63) redD[tid >> 6] = wmn;
      __syncthreads();
      float mr = fminf(fminf(redD[0], redD[1]), fminf(redD[2], redD[3]));
      float kd = exact ? 0.9f : 0.95f;
      float t = fminf(1.f, kd * mr);
      if (act){
        y = fmaxf(fmaf(t, dy, y), 1e-12f);
        yv[row] = y;
        put_ph(phs, row, y);                     // repack y for next f16 use
      }
    }

    if (!exact && (gg <= P1_EXIT * gg0 || it + 1 >= N_PH1)) ph1done = true;
  }

  // ---- z = y / sum(y) (output 1) ----
  float wy = dpp_wave_sum(act ? y : 0.f);
  if ((tid & 63) == 63) red4[tid >> 6] = make_float4(wy, 0.f, 0.f, 0.f);
  __syncthreads();
  float ys = (red4[0].x + red4[1].x) + (red4[2].x + red4[3].x);
  if (act) out[(size_t)s * NA + row] = y / ys;
}

extern "C" void kernel_launch(void* const* d_in, const int* in_sizes, int n_in,
                              void* d_out, int out_size, void* d_ws, size_t ws_size,
                              hipStream_t stream) {
  const float* x     = (const float*)d_in[0];
  const float* Sigma = (const float*)d_in[1];
  const float* W1    = (const float*)d_in[2];
  const float* b1    = (const float*)d_in[3];
  const float* W2    = (const float*)d_in[4];
  const float* b2    = (const float*)d_in[5];
  float* out = (float*)d_out;
  hipLaunchKernelGGL(rb_kernel, dim3(B_SAMPLES), dim3(NTHREADS), 0, stream,
                     x, Sigma, W1, b1, W2, b2, out);
}

// Round 9
// 337.387 us; speedup vs baseline: 1.6753x; 1.0258x over previous
//
#include <hip/hip_runtime.h>
#include <math.h>

#define NF        128
#define H_DIM     256
#define NA        200
#define B_SAMPLES 512
#define ALPHA_LR  0.01f
#define B_MIN_C   1e-4f

#define NTHREADS  256               // 4 waves: thread t owns full row t (t<200)
#define ROWS_PER_WAVE 50            // exact-path: 4 waves x 50 rows

#define N_PH1     10
#define N_REFINE  1
#define CG_MAX    32
#define TOL2_LO   4e-4f             // refinement CG tolerance (accuracy anchor)
#define TOL2_P1   4e-3f             // phase-1 CG tolerance floor
#define TOL2_HI   6e-2f             // phase-1 CG tolerance cap
#define P1_FACT   8.f               // adaptive factor
#define P1_EXIT   1e-7f             // phase-1 Newton early-exit

typedef _Float16 h2_t __attribute__((ext_vector_type(2)));
typedef unsigned uv4  __attribute__((ext_vector_type(4)));

__device__ __forceinline__ h2_t as_h2(unsigned u){
  union { unsigned u; h2_t h; } c; c.u = u; return c.h;
}
__device__ __forceinline__ unsigned pk_f16(float a, float b){
#if __has_builtin(__builtin_amdgcn_cvt_pkrtz)
  union { decltype(__builtin_amdgcn_cvt_pkrtz(0.f, 0.f)) h; unsigned u; } c;
  c.h = __builtin_amdgcn_cvt_pkrtz(a, b);
  return c.u;
#else
  union { h2_t h; unsigned u; } c;
  c.h = (h2_t){ (_Float16)a, (_Float16)b };
  return c.u;
#endif
}
__device__ __forceinline__ float fdot2(unsigned m, unsigned v, float acc){
#if __has_builtin(__builtin_amdgcn_fdot2)
  return __builtin_amdgcn_fdot2(as_h2(m), as_h2(v), acc, false);
#else
  h2_t a = as_h2(m), b = as_h2(v);
  return fmaf((float)a.y, (float)b.y, fmaf((float)a.x, (float)b.x, acc));
#endif
}
// fast reciprocal (v_rcp_f32, ~1e-7 rel) for loop-carried scalar chain
__device__ __forceinline__ float fast_rcp(float x){
#if __has_builtin(__builtin_amdgcn_rcpf)
  return __builtin_amdgcn_rcpf(x);
#else
  return 1.f / x;
#endif
}

// ---------------- DPP wave-64 reductions (result valid in lane 63) --------
__device__ __forceinline__ float dpp_wave_sum(float v){
  v += __int_as_float(__builtin_amdgcn_update_dpp(0, __float_as_int(v), 0x111, 0xf, 0xf, false));
  v += __int_as_float(__builtin_amdgcn_update_dpp(0, __float_as_int(v), 0x112, 0xf, 0xf, false));
  v += __int_as_float(__builtin_amdgcn_update_dpp(0, __float_as_int(v), 0x114, 0xf, 0xf, false));
  v += __int_as_float(__builtin_amdgcn_update_dpp(0, __float_as_int(v), 0x118, 0xf, 0xf, false));
  v += __int_as_float(__builtin_amdgcn_update_dpp(0, __float_as_int(v), 0x142, 0xa, 0xf, false));
  v += __int_as_float(__builtin_amdgcn_update_dpp(0, __float_as_int(v), 0x143, 0xc, 0xf, false));
  return v;
}
__device__ __forceinline__ float dpp_wave_min(float v){
  const int PINF = 0x7f800000;
  v = fminf(v, __int_as_float(__builtin_amdgcn_update_dpp(PINF, __float_as_int(v), 0x111, 0xf, 0xf, false)));
  v = fminf(v, __int_as_float(__builtin_amdgcn_update_dpp(PINF, __float_as_int(v), 0x112, 0xf, 0xf, false)));
  v = fminf(v, __int_as_float(__builtin_amdgcn_update_dpp(PINF, __float_as_int(v), 0x114, 0xf, 0xf, false)));
  v = fminf(v, __int_as_float(__builtin_amdgcn_update_dpp(PINF, __float_as_int(v), 0x118, 0xf, 0xf, false)));
  v = fminf(v, __int_as_float(__builtin_amdgcn_update_dpp(PINF, __float_as_int(v), 0x142, 0xa, 0xf, false)));
  v = fminf(v, __int_as_float(__builtin_amdgcn_update_dpp(PINF, __float_as_int(v), 0x143, 0xc, 0xf, false)));
  return v;
}
__device__ __forceinline__ float dpp_wave_max(float v){
  const int NINF = 0xff800000;
  v = fmaxf(v, __int_as_float(__builtin_amdgcn_update_dpp(NINF, __float_as_int(v), 0x111, 0xf, 0xf, false)));
  v = fmaxf(v, __int_as_float(__builtin_amdgcn_update_dpp(NINF, __float_as_int(v), 0x112, 0xf, 0xf, false)));
  v = fmaxf(v, __int_as_float(__builtin_amdgcn_update_dpp(NINF, __float_as_int(v), 0x114, 0xf, 0xf, false)));
  v = fmaxf(v, __int_as_float(__builtin_amdgcn_update_dpp(NINF, __float_as_int(v), 0x118, 0xf, 0xf, false)));
  v = fmaxf(v, __int_as_float(__builtin_amdgcn_update_dpp(NINF, __float_as_int(v), 0x142, 0xa, 0xf, false)));
  v = fmaxf(v, __int_as_float(__builtin_amdgcn_update_dpp(NINF, __float_as_int(v), 0x143, 0xc, 0xf, false)));
  return v;
}
// block reductions over 4 waves (prologue only)
__device__ __forceinline__ float block_sum4(float v, float* red, int tid){
  __syncthreads();
  v = dpp_wave_sum(v);
  if ((tid & 63) == 63) red[tid >> 6] = v;
  __syncthreads();
  return (red[0] + red[1]) + (red[2] + red[3]);
}
__device__ __forceinline__ float block_max4(float v, float* red, int tid){
  __syncthreads();
  v = dpp_wave_max(v);
  if ((tid & 63) == 63) red[tid >> 6] = v;
  __syncthreads();
  return fmaxf(fmaxf(red[0], red[1]), fmaxf(red[2], red[3]));
}

// owner writes its f16 vector entry (rows 0..199 contiguous)
__device__ __forceinline__ void put_ph(unsigned short* phs, int row, float v){
  phs[row] = (unsigned short)(pk_f16(v, 0.f) & 0xffffu);
}

// packed-f16 full-row matvec: 100 dwords from VGPRs.
// Prefetch ALL 25 p-quads first (one LDS-latency exposure, not five).
__device__ __forceinline__ float mv_dot2(const unsigned* mreg,
                                         const unsigned* __restrict__ ph){
  const uv4* v4 = (const uv4*)ph;
  uv4 pv[25];
  #pragma unroll
  for (int k = 0; k < 25; ++k) pv[k] = v4[k];
  float a0=0.f, a1=0.f, a2=0.f, a3=0.f;
  #pragma unroll
  for (int k = 0; k < 25; ++k){
    a0 = fdot2(mreg[4*k+0], pv[k].x, a0);
    a1 = fdot2(mreg[4*k+1], pv[k].y, a1);
    a2 = fdot2(mreg[4*k+2], pv[k].z, a2);
    a3 = fdot2(mreg[4*k+3], pv[k].w, a3);
  }
  return (a0 + a1) + (a2 + a3);
}

// f16-matrix x fp32-vector (phase-1 gradient: exact fixed point of f16 system)
__device__ __forceinline__ float mv_f32v(const unsigned* mreg,
                                         const float* __restrict__ vv){
  const float4* v4 = (const float4*)vv;
  float a0=0.f, a1=0.f, a2=0.f, a3=0.f;
  #pragma unroll
  for (int k = 0; k < 25; ++k){
    float4 va = v4[2*k], vb = v4[2*k+1];
    h2_t m0 = as_h2(mreg[4*k+0]), m1 = as_h2(mreg[4*k+1]);
    h2_t m2 = as_h2(mreg[4*k+2]), m3 = as_h2(mreg[4*k+3]);
    a0 = fmaf((float)m0.x, va.x, a0); a1 = fmaf((float)m0.y, va.y, a1);
    a2 = fmaf((float)m1.x, va.z, a2); a3 = fmaf((float)m1.y, va.w, a3);
    a0 = fmaf((float)m2.x, vb.x, a0); a1 = fmaf((float)m2.y, vb.y, a1);
    a2 = fmaf((float)m3.x, vb.z, a2); a3 = fmaf((float)m3.y, vb.w, a3);
  }
  return (a0 + a1) + (a2 + a3);
}

// R9: NO 2nd launch_bounds arg. R8 measured: "(256,2)" CLAMPS the allocator
// to 128 VGPRs (not 256 as modeled) -> mreg+pv spill -> 51MB scratch writes,
// 247MB fetch. Bare form lets the compiler take ~170 (2 waves/SIMD, no spill).
extern "C" __global__ __launch_bounds__(NTHREADS)
void rb_kernel(const float* __restrict__ x,  const float* __restrict__ Sigma,
               const float* __restrict__ W1, const float* __restrict__ b1,
               const float* __restrict__ W2, const float* __restrict__ b2,
               float* __restrict__ out) {
  __shared__ __align__(16) unsigned ph[100];          // packed f16 vector (200 h)
  __shared__ __align__(16) float yv[NA];
  __shared__ __align__(16) float partial[NA];
  __shared__ float xs[NF];
  __shared__ float hs[H_DIM];
  __shared__ __align__(16) float4 red4[4];            // fused CG reduction slots
  __shared__ float redD[4], red8[4];

  const int tid  = threadIdx.x;
  const int s    = blockIdx.x;
  const bool act = tid < NA;                          // thread t owns row t
  const int row  = tid;
  const float* S = Sigma + (size_t)s * NA * NA;
  unsigned short* phs = (unsigned short*)ph;

  if (tid < NF) xs[tid] = x[s * NF + tid];
  float sd = act ? S[(size_t)row * NA + row] : 0.f;

  // ---- stage Sigma row (packed f16): 100 dwords -> VGPRs ----
  unsigned mreg[100];
  if (act){
    const float4* rowp = (const float4*)(S + (size_t)row * NA);
    #pragma unroll
    for (int k = 0; k < 50; ++k){
      float4 w = rowp[k];
      mreg[2*k]   = pk_f16(w.x, w.y);
      mreg[2*k+1] = pk_f16(w.z, w.w);
    }
  }

  // ---- MLP ----
  __syncthreads();                        // xs visible
  {
    const float* w = W1 + tid * NF;       // tid < 256 == H_DIM
    float acc = b1[tid];
    #pragma unroll 8
    for (int j = 0; j < NF; ++j) acc = fmaf(w[j], xs[j], acc);
    hs[tid] = (acc >= 0.f) ? acc : ALPHA_LR * acc;
  }
  __syncthreads();
  float logit = -INFINITY;
  if (act){
    const float* w = W2 + row * H_DIM;
    float acc = b2[row];
    #pragma unroll 8
    for (int j = 0; j < H_DIM; ++j) acc = fmaf(w[j], hs[j], acc);
    logit = acc;
  }

  // ---- softmax -> b (output 2); clamp+renorm -> b_ (local, row==tid) ----
  float mx = block_max4(logit, red8, tid);
  float e  = act ? expf(logit - mx) : 0.f;
  float es = block_sum4(e, red8, tid);
  float bsoft = e / es;
  if (act) out[(size_t)B_SAMPLES * NA + (size_t)s * NA + row] = bsoft;
  float bcl = fmaxf(bsoft, B_MIN_C);
  float bs  = block_sum4(act ? bcl : 0.f, red8, tid);

  float b_ = 0.f, y = 0.f;
  if (act){ b_ = bcl / bs; put_ph(phs, row, b_); }

  // ---- y0 = bc / sqrt(bc^T S bc) ----
  __syncthreads();                               // ph visible
  {
    float acc = act ? mv_dot2(mreg, ph) : 0.f;
    float wq  = dpp_wave_sum(act ? b_ * acc : 0.f);
    if ((tid & 63) == 63) red4[tid >> 6] = make_float4(wq, 0.f, 0.f, 0.f);
    __syncthreads();
    float quad = (red4[0].x + red4[1].x) + (red4[2].x + red4[3].x);
    if (act){ y = b_ / sqrtf(quad); yv[row] = y; }
  }

  // ---- damped inexact Newton ----
  float gg0 = 1.f;
  bool  ph1done = false;
  int   nexact  = 0;
  for (int it = 0; it < N_PH1 + N_REFINE; ++it){
    if (nexact >= N_REFINE) break;
    const bool exact = ph1done;
    if (exact) ++nexact;

    // --- gradient matvec q = (S y)_row (fp32 y, f16 or exact matrix) ---
    float q = 0.f;
    if (exact){
      __syncthreads();                           // yv visible, partial free
      int lane = tid & 63, wid = tid >> 6;
      int r0 = wid * ROWS_PER_WAVE;
      for (int rr = r0; rr < r0 + ROWS_PER_WAVE; ++rr){
        const float* rowp = S + (size_t)rr * NA;
        float a = rowp[lane]*yv[lane] + rowp[lane+64]*yv[lane+64]
                + rowp[lane+128]*yv[lane+128];
        if (lane < NA - 192) a += rowp[lane+192]*yv[lane+192];
        a = dpp_wave_sum(a);
        if (lane == 63) partial[rr] = a;
      }
      __syncthreads();
      if (act) q = partial[row];
    } else {
      __syncthreads();                           // yv visible
      q = act ? mv_f32v(mreg, yv) : 0.f;
    }

    // --- Newton init; reduce gg and rz together ---
    float g=0.f, d=0.f, mi=0.f;
    if (act){
      float ry = fast_rcp(y);
      g  = q - b_ * ry;
      d  = b_ * ry * ry;
      mi = fast_rcp(sd + d);
    }
    float wg = dpp_wave_sum(act ? g * g : 0.f);
    float wz = dpp_wave_sum(act ? g * g * mi : 0.f);   // rz = g^T M^-1 g
    if ((tid & 63) == 63) red4[tid >> 6] = make_float4(wg, wz, 0.f, 0.f);
    __syncthreads();
    float4 t0 = red4[0], t1 = red4[1], t2 = red4[2], t3 = red4[3];
    float gg = (t0.x + t1.x) + (t2.x + t3.x);
    float rz = (t0.y + t1.y) + (t2.y + t3.y);
    if (it == 0) gg0 = fmaxf(gg, 1e-30f);
    float tol2 = exact ? TOL2_LO
                       : fminf(TOL2_HI, fmaxf(TOL2_P1, P1_FACT * (gg / gg0)));

    if (gg > 1e-24f){
      // --- scale CG system by 1/||g|| so packed-f16 p never underflows ---
      const float cinv = rsqrtf(gg);
      const float csc  = sqrtf(gg);
      float r=0.f, z=0.f, dy=0.f, pj=0.f;
      if (act){
        r  = -g * cinv;
        z  = mi * r;
        pj = z;
        put_ph(phs, row, pj);
      }
      rz = rz * cinv * cinv;

      // --- Jacobi-PCG, fused single reduction (pq, rq, qq in one float4) ---
      const float rz0 = rz;
      for (int j = 0; j < CG_MAX; ++j){
        __syncthreads();                         // B1: ph visible, red4 reuse safe
        float qp = act ? mv_dot2(mreg, ph) : 0.f;
        float qf=0.f, cpq=0.f, crq=0.f, cqq=0.f;
        if (act){
          qf = qp + d * pj;
          float u = mi * qf;
          cpq = pj * qf; crq = r * u; cqq = qf * u;
        }
        cpq = dpp_wave_sum(cpq); crq = dpp_wave_sum(crq); cqq = dpp_wave_sum(cqq);
        if ((tid & 63) == 63) red4[tid >> 6] = make_float4(cpq, crq, cqq, 0.f);
        __syncthreads();                         // B2
        float4 u0 = red4[0], u1 = red4[1], u2 = red4[2], u3 = red4[3];
        float pq = (u0.x + u1.x) + (u2.x + u3.x);
        float rq = (u0.y + u1.y) + (u2.y + u3.y);
        float qq = (u0.z + u1.z) + (u2.z + u3.z);
        float alpha = rz * fast_rcp(pq);
        float rznew = fmaxf(fmaf(alpha*alpha, qq, fmaf(-2.f*alpha, rq, rz)), 0.f);
        if (act){
          dy = fmaf(alpha, pj, dy);
          r  = fmaf(-alpha, qf, r);
          z  = mi * r;
        }
        bool brk = (rznew <= tol2 * rz0) || (j == CG_MAX - 1);
        if (!brk){
          float beta = rznew * fast_rcp(rz);
          if (act){ pj = fmaf(beta, pj, z); put_ph(phs, row, pj); }
        }
        rz = rznew;
        if (brk) break;
      }

      // --- unscale dy; damped step keeping y > 0.
      // Phase-1 uses 0.95 fraction-to-boundary (faster warm-up); the exact
      // refinement keeps reference 0.9. ---
      if (act) dy *= csc;
      float ratio = (act && dy < 0.f) ? (-y / dy) : 1e30f;
      float wmn = dpp_wave_min(ratio);
      if ((tid & 63) == 63) redD[tid >> 6] = wmn;
      __syncthreads();
      float mr = fminf(fminf(redD[0], redD[1]), fminf(redD[2], redD[3]));
      float kd = exact ? 0.9f : 0.95f;
      float t = fminf(1.f, kd * mr);
      if (act){
        y = fmaxf(fmaf(t, dy, y), 1e-12f);
        yv[row] = y;
        put_ph(phs, row, y);                     // repack y for next f16 use
      }
    }

    if (!exact && (gg <= P1_EXIT * gg0 || it + 1 >= N_PH1)) ph1done = true;
  }

  // ---- z = y / sum(y) (output 1) ----
  float wy = dpp_wave_sum(act ? y : 0.f);
  if ((tid & 63) == 63) red4[tid >> 6] = make_float4(wy, 0.f, 0.f, 0.f);
  __syncthreads();
  float ys = (red4[0].x + red4[1].x) + (red4[2].x + red4[3].x);
  if (act) out[(size_t)s * NA + row] = y / ys;
}

extern "C" void kernel_launch(void* const* d_in, const int* in_sizes, int n_in,
                              void* d_out, int out_size, void* d_ws, size_t ws_size,
                              hipStream_t stream) {
  const float* x     = (const float*)d_in[0];
  const float* Sigma = (const float*)d_in[1];
  const float* W1    = (const float*)d_in[2];
  const float* b1    = (const float*)d_in[3];
  const float* W2    = (const float*)d_in[4];
  const float* b2    = (const float*)d_in[5];
  float* out = (float*)d_out;
  hipLaunchKernelGGL(rb_kernel, dim3(B_SAMPLES), dim3(NTHREADS), 0, stream,
                     x, Sigma, W1, b1, W2, b2, out);
}